// Round 1
// baseline (394.135 us; speedup 1.0000x reference)
//
#include <hip/hip_runtime.h>
#include <stdint.h>

#define NB 16
#define HH 512
#define WW 512
#define HW (HH*WW)          // 262144
#define NBINS 4096

__device__ __forceinline__ float clip01(float v){ return fminf(fmaxf(v, 0.0f), 1.0f); }
__device__ __forceinline__ int refl(int i, int n){ if (i < 0) i = -i; if (i >= n) i = 2*n - 2 - i; return i; }
__device__ __forceinline__ int clampi(int i, int lo, int hi){ return i < lo ? lo : (i > hi ? hi : i); }

// ---------------- init per-image stats ----------------
// stats[img*4+0] = min edge-density bits (u32-ordered nonneg float), init FLT_MAX
// stats[img*4+1] = max edge-density bits, init 0.0
// stats[img*4+2] = min sparsity (float bits), written by k_spb
// stats[img*4+3] = max sparsity (float bits), written by k_spb
__global__ void k_init(uint32_t* stats){
  int i = threadIdx.x;
  if (i < NB){ stats[i*4+0] = 0x7F7FFFFFu; stats[i*4+1] = 0u; stats[i*4+2] = 0u; stats[i*4+3] = 0u; }
}

// ---------------- denorm + gray + quantized bins + histogram ----------------
__global__ void k_prep(const float* __restrict__ x, const float* __restrict__ mean,
                       const float* __restrict__ stdv, float* __restrict__ gray,
                       uint16_t* __restrict__ comb, uint32_t* __restrict__ hist)
{
#pragma clang fp contract(off)
  __shared__ uint32_t h[NBINS];
  for (int i = threadIdx.x; i < NBINS; i += blockDim.x) h[i] = 0u;
  __syncthreads();
  int img  = blockIdx.x >> 4;
  int base = (blockIdx.x & 15) * 16384;
  float m0 = mean[0], m1 = mean[1], m2 = mean[2];
  float s0 = stdv[0], s1 = stdv[1], s2 = stdv[2];
  const float* xb = x + (size_t)img * 3 * HW;
  for (int i = threadIdx.x; i < 16384; i += blockDim.x){
    int p = base + i;
    float xr = clip01(xb[p]        * s0 + m0);
    float xg = clip01(xb[HW + p]   * s1 + m1);
    float xbl= clip01(xb[2*HW + p] * s2 + m2);
    float gy = 0.299f*xr + 0.587f*xg + 0.114f*xbl;
    gray[(size_t)img*HW + p] = gy;
    int c = ((int)rintf(xr*15.0f))*256 + ((int)rintf(xg*15.0f))*16 + (int)rintf(xbl*15.0f);
    comb[(size_t)img*HW + p] = (uint16_t)c;
    atomicAdd(&h[c], 1u);
  }
  __syncthreads();
  uint32_t* gh = hist + img * NBINS;
  for (int i = threadIdx.x; i < NBINS; i += blockDim.x){ uint32_t v = h[i]; if (v) atomicAdd(&gh[i], v); }
}

// ---------------- sparsity min/max from histogram ----------------
__global__ void k_spb(const uint32_t* __restrict__ hist, uint32_t* __restrict__ stats){
  int img = blockIdx.x;
  uint32_t mx = 0u, mn = 0xFFFFFFFFu;
  for (int i = threadIdx.x; i < NBINS; i += 256){
    uint32_t c = hist[img*NBINS + i];
    if (c > mx) mx = c;
    if (c > 0u && c < mn) mn = c;
  }
  __shared__ uint32_t rmx[256], rmn[256];
  rmx[threadIdx.x] = mx; rmn[threadIdx.x] = mn;
  __syncthreads();
  for (int s = 128; s > 0; s >>= 1){
    if (threadIdx.x < (unsigned)s){
      rmx[threadIdx.x] = max(rmx[threadIdx.x], rmx[threadIdx.x + s]);
      rmn[threadIdx.x] = min(rmn[threadIdx.x], rmn[threadIdx.x + s]);
    }
    __syncthreads();
  }
  if (threadIdx.x == 0){
    float sp_min = -logf((float)rmx[0] / 262144.0f + 1e-9f);   // most frequent bin
    float sp_max = -logf((float)rmn[0] / 262144.0f + 1e-9f);   // rarest occupied bin
    stats[img*4+2] = __float_as_uint(sp_min);
    stats[img*4+3] = __float_as_uint(sp_max);
  }
}

// ---------------- 5x5 Gaussian blur (sigma=1), reflect pad ----------------
__global__ void k_blur5(const float* __restrict__ gray, float* __restrict__ out)
{
#pragma clang fp contract(off)
  int idx = blockIdx.x * 256 + threadIdx.x;
  int img = idx >> 18;
  int p   = idx & (HW - 1);
  int y = p >> 9, xc = p & 511;
  float g[5]; float s = 0.0f;
  for (int i = 0; i < 5; i++){ float t = (float)i - 2.0f; g[i] = expf(-(t*t)/2.0f); s += g[i]; }
  for (int i = 0; i < 5; i++) g[i] /= s;
  const float* gb = gray + (size_t)img*HW;
  float acc = 0.0f;
  for (int ky = 0; ky < 5; ky++){
    int yy = refl(y + ky - 2, HH);
    const float* row = gb + yy*WW;
    for (int kx = 0; kx < 5; kx++){
      int xx = refl(xc + kx - 2, WW);
      acc += (g[ky]*g[kx]) * row[xx];
    }
  }
  out[idx] = acc;
}

// ---------------- Sobel (edge/replicate pad) -> mag + direction ----------------
__global__ void k_sobel(const float* __restrict__ blur, float* __restrict__ mag, uint8_t* __restrict__ dir)
{
#pragma clang fp contract(off)
  int idx = blockIdx.x * 256 + threadIdx.x;
  int img = idx >> 18;
  int p   = idx & (HW - 1);
  int y = p >> 9, xc = p & 511;
  const float* b = blur + (size_t)img*HW;
  float v[3][3];
  for (int dy = 0; dy < 3; dy++){
    int yy = clampi(y + dy - 1, 0, HH-1);
    for (int dx = 0; dx < 3; dx++){
      int xx = clampi(xc + dx - 1, 0, WW-1);
      v[dy][dx] = b[yy*WW + xx];
    }
  }
  float gx = (v[0][2] - v[0][0]) + 2.0f*(v[1][2] - v[1][0]) + (v[2][2] - v[2][0]);
  float gy = (v[2][0] + 2.0f*v[2][1] + v[2][2]) - (v[0][0] + 2.0f*v[0][1] + v[0][2]);
  float m = sqrtf(gx*gx + gy*gy + 1e-6f);
  float ang = atan2f(gy, gx) * 57.29577951308232f;
  int ai = (int)rintf(ang / 45.0f);           // [-4,4], round-half-even like jnp.round
  mag[idx] = m;
  dir[idx] = (uint8_t)(ai & 7);
}

// ---------------- NMS + double threshold -> bitmasks (weak, strong) ----------------
__global__ void k_nms(const float* __restrict__ mag, const uint8_t* __restrict__ dir,
                      unsigned long long* __restrict__ A, unsigned long long* __restrict__ S)
{
  int idx = blockIdx.x * 256 + threadIdx.x;
  int img = idx >> 18;
  int p   = idx & (HW - 1);
  int y = p >> 9, xc = p & 511;
  const float* mb = mag + (size_t)img*HW;
  float m = mb[p];
  int d  = dir[idx];
  int d2 = (d + 4) & 7;
  const int OY[8] = {0,1,1,1,0,-1,-1,-1};
  const int OX[8] = {1,1,0,-1,-1,-1,0,1};
  float mp = 0.0f, mn = 0.0f;
  { int yy = y + OY[d],  xx = xc + OX[d];  if (yy>=0 && yy<HH && xx>=0 && xx<WW) mp = mb[yy*WW+xx]; }
  { int yy = y + OY[d2], xx = xc + OX[d2]; if (yy>=0 && yy<HH && xx>=0 && xx<WW) mn = mb[yy*WW+xx]; }
  bool keep = ((m - mp) > 0.0f) && ((m - mn) > 0.0f);
  float mf = keep ? m : 0.0f;
  bool strong = mf > 0.2f;
  bool weak   = (mf > 0.1f) && !(mf > 0.2f);
  unsigned long long wb = __ballot(weak);
  unsigned long long sb = __ballot(strong);
  if ((threadIdx.x & 63) == 0){ A[idx >> 6] = wb; S[idx >> 6] = sb; }
}

// ---------------- hysteresis fixpoint on bitmasks, one block per image ----------------
__device__ __forceinline__ bool hyst_update(unsigned long long (*sS)[8],
                                            const unsigned long long (*sP)[8],
                                            int r, int w)
{
  unsigned long long P = sP[r][w];
  if (!P) return false;
  unsigned long long Sv = sS[r][w];
  unsigned long long nb = 0ull;
  #pragma unroll
  for (int k = 0; k < 3; k++){
    int rr = r + k - 1;
    if (rr < 0 || rr >= HH) continue;
    unsigned long long xm = sS[rr][w];
    unsigned long long xl = (w > 0) ? sS[rr][w-1] : 0ull;
    unsigned long long xr = (w < 7) ? sS[rr][w+1] : 0ull;
    nb |= xm | (xm << 1) | (xl >> 63) | (xm >> 1) | (xr << 63);
  }
  unsigned long long g = Sv | (P & nb);
  if (g == Sv) return false;
  // Kogge-Stone masked flood within the 64-bit word, both directions
  unsigned long long p1 = P, g1 = g;
  g1 |= p1 & (g1 << 1);  p1 &= (p1 << 1);
  g1 |= p1 & (g1 << 2);  p1 &= (p1 << 2);
  g1 |= p1 & (g1 << 4);  p1 &= (p1 << 4);
  g1 |= p1 & (g1 << 8);  p1 &= (p1 << 8);
  g1 |= p1 & (g1 << 16); p1 &= (p1 << 16);
  g1 |= p1 & (g1 << 32);
  unsigned long long p2 = P, g2 = g;
  g2 |= p2 & (g2 >> 1);  p2 &= (p2 >> 1);
  g2 |= p2 & (g2 >> 2);  p2 &= (p2 >> 2);
  g2 |= p2 & (g2 >> 4);  p2 &= (p2 >> 4);
  g2 |= p2 & (g2 >> 8);  p2 &= (p2 >> 8);
  g2 |= p2 & (g2 >> 16); p2 &= (p2 >> 16);
  g2 |= p2 & (g2 >> 32);
  unsigned long long ns = g1 | g2;
  if (ns != Sv){ sS[r][w] = ns; return true; }
  return false;
}

__global__ void __launch_bounds__(512) k_hyst(const unsigned long long* __restrict__ A,
                                              unsigned long long* __restrict__ S)
{
  __shared__ unsigned long long sS[HH][8];   // 32 KiB
  __shared__ unsigned long long sP[HH][8];   // 32 KiB
  int img = blockIdx.x;
  const unsigned long long* gA = A + img * 4096;
  unsigned long long*       gS = S + img * 4096;
  for (int i = threadIdx.x; i < 4096; i += 512){
    unsigned long long sv = gS[i];
    sS[i >> 3][i & 7] = sv;
    sP[i >> 3][i & 7] = gA[i] | sv;     // propagate mask = weak | strong
  }
  __syncthreads();
  int w  = threadIdx.x & 7;
  int r0 = (threadIdx.x >> 3) << 3;     // 8 rows per thread
  for (;;){
    bool c = false;
    for (int r = r0;     r < r0 + 8; r++) c |= hyst_update(sS, sP, r, w);
    for (int r = r0 + 7; r >= r0;    r--) c |= hyst_update(sS, sP, r, w);
    if (!__syncthreads_or(c ? 1 : 0)) break;
  }
  for (int i = threadIdx.x; i < 4096; i += 512) gS[i] = sS[i >> 3][i & 7];
}

// ---------------- bits -> float edges ----------------
__global__ void k_b2f(const unsigned long long* __restrict__ S, float* __restrict__ out){
  int idx = blockIdx.x * 256 + threadIdx.x;
  out[idx] = (float)((S[idx >> 6] >> (idx & 63)) & 1ull);
}

// ---------------- 11-tap Gaussian (sigma=1.5), separable, reflect pad ----------------
__global__ void k_b11h(const float* __restrict__ in, float* __restrict__ out)
{
#pragma clang fp contract(off)
  int idx = blockIdx.x * 256 + threadIdx.x;
  int img = idx >> 18;
  int p   = idx & (HW - 1);
  int y = p >> 9, xc = p & 511;
  float g[11]; float s = 0.0f;
  for (int i = 0; i < 11; i++){ float t = (float)i - 5.0f; g[i] = expf(-(t*t)/4.5f); s += g[i]; }
  for (int i = 0; i < 11; i++) g[i] /= s;
  const float* row = in + (size_t)img*HW + y*WW;
  float acc = 0.0f;
  for (int k = 0; k < 11; k++){ int xx = refl(xc + k - 5, WW); acc += g[k] * row[xx]; }
  out[idx] = acc;
}

__global__ void k_b11v(const float* __restrict__ in, float* __restrict__ out, uint32_t* __restrict__ stats)
{
#pragma clang fp contract(off)
  int idx = blockIdx.x * 256 + threadIdx.x;
  int img = idx >> 18;
  int p   = idx & (HW - 1);
  int y = p >> 9, xc = p & 511;
  float g[11]; float s = 0.0f;
  for (int i = 0; i < 11; i++){ float t = (float)i - 5.0f; g[i] = expf(-(t*t)/4.5f); s += g[i]; }
  for (int i = 0; i < 11; i++) g[i] /= s;
  const float* ib = in + (size_t)img*HW;
  float acc = 0.0f;
  for (int k = 0; k < 11; k++){ int yy = refl(y + k - 5, HH); acc += g[k] * ib[yy*WW + xc]; }
  out[idx] = acc;
  // fused per-image min/max (values >= 0 so u32-ordered)
  float mn = acc, mx = acc;
  for (int off = 32; off >= 1; off >>= 1){
    mn = fminf(mn, __shfl_down(mn, off));
    mx = fmaxf(mx, __shfl_down(mx, off));
  }
  __shared__ float smn[4], smx[4];
  int wv = threadIdx.x >> 6, ln = threadIdx.x & 63;
  if (ln == 0){ smn[wv] = mn; smx[wv] = mx; }
  __syncthreads();
  if (threadIdx.x == 0){
    float a = fminf(fminf(smn[0], smn[1]), fminf(smn[2], smn[3]));
    float b = fmaxf(fmaxf(smx[0], smx[1]), fmaxf(smx[2], smx[3]));
    atomicMin(&stats[img*4+0], __float_as_uint(a));
    atomicMax(&stats[img*4+1], __float_as_uint(b));
  }
}

// ---------------- fuse: normalize both maps, sigmoid ----------------
__global__ void k_final(const float* __restrict__ ed, const uint16_t* __restrict__ comb,
                        const uint32_t* __restrict__ hist, const uint32_t* __restrict__ stats,
                        const float* __restrict__ alpha, const float* __restrict__ beta,
                        float* __restrict__ out)
{
#pragma clang fp contract(off)
  int idx = blockIdx.x * 256 + threadIdx.x;
  int img = idx >> 18;
  float a = alpha[0], b = beta[0];
  float mne = __uint_as_float(stats[img*4+0]);
  float mxe = __uint_as_float(stats[img*4+1]);
  float mns = __uint_as_float(stats[img*4+2]);
  float mxs = __uint_as_float(stats[img*4+3]);
  float e  = ed[idx];
  float sp = -logf((float)hist[img*NBINS + comb[idx]] / 262144.0f + 1e-9f);
  float en = (e  - mne) / (mxe - mne + 1e-9f);
  float sn = (sp - mns) / (mxs - mns + 1e-9f);
  float f  = a*en + b*sn;
  out[idx] = 1.0f / (1.0f + expf(-f));
}

extern "C" void kernel_launch(void* const* d_in, const int* in_sizes, int n_in,
                              void* d_out, int out_size, void* d_ws, size_t ws_size,
                              hipStream_t stream)
{
  const float* x     = (const float*)d_in[0];
  const float* mean  = (const float*)d_in[1];
  const float* stdv  = (const float*)d_in[2];
  const float* alpha = (const float*)d_in[3];
  const float* beta  = (const float*)d_in[4];
  float* out = (float*)d_out;

  char* ws = (char*)d_ws;
  float*              buf0  = (float*)ws;                                   // 16 MB (gray -> mag -> tmp11)
  uint16_t*           comb  = (uint16_t*)(ws + (16u << 20));                // 8 MB
  uint8_t*            dir   = (uint8_t*)(ws + (24u << 20));                 // 4 MB
  uint32_t*           hist  = (uint32_t*)(ws + (28u << 20));                // 256 KB
  unsigned long long* Ab    = (unsigned long long*)(ws + (28u << 20) + (1u << 18));               // 512 KB
  unsigned long long* Sb    = (unsigned long long*)(ws + (28u << 20) + (1u << 18) + (1u << 19));  // 512 KB
  uint32_t*           stats = (uint32_t*)(ws + (28u << 20) + (1u << 18) + (2u << 19));            // 256 B

  hipMemsetAsync(hist, 0, NB * NBINS * sizeof(uint32_t), stream);
  hipLaunchKernelGGL(k_init, dim3(1), dim3(64), 0, stream, stats);
  hipLaunchKernelGGL(k_prep, dim3(256), dim3(256), 0, stream, x, mean, stdv, buf0, comb, hist);
  hipLaunchKernelGGL(k_spb,  dim3(NB), dim3(256), 0, stream, hist, stats);
  hipLaunchKernelGGL(k_blur5, dim3(16384), dim3(256), 0, stream, buf0, out);         // blurred -> d_out
  hipLaunchKernelGGL(k_sobel, dim3(16384), dim3(256), 0, stream, out, buf0, dir);    // mag -> buf0
  hipLaunchKernelGGL(k_nms,   dim3(16384), dim3(256), 0, stream, buf0, dir, Ab, Sb);
  hipLaunchKernelGGL(k_hyst,  dim3(NB), dim3(512), 0, stream, Ab, Sb);
  hipLaunchKernelGGL(k_b2f,   dim3(16384), dim3(256), 0, stream, Sb, out);           // edges -> d_out
  hipLaunchKernelGGL(k_b11h,  dim3(16384), dim3(256), 0, stream, out, buf0);         // tmp -> buf0
  hipLaunchKernelGGL(k_b11v,  dim3(16384), dim3(256), 0, stream, buf0, out, stats);  // density -> d_out
  hipLaunchKernelGGL(k_final, dim3(16384), dim3(256), 0, stream, out, comb, hist, stats, alpha, beta, out);
}

// Round 2
// 190.814 us; speedup vs baseline: 2.0655x; 2.0655x over previous
//
#include <hip/hip_runtime.h>
#include <stdint.h>

#define NB 16
#define HH 512
#define WW 512
#define HW (HH*WW)          // 262144
#define NBINS 4096

__device__ __forceinline__ float clip01(float v){ return fminf(fmaxf(v, 0.0f), 1.0f); }
__device__ __forceinline__ int refl(int i, int n){ if (i < 0) i = -i; if (i >= n) i = 2*n - 2 - i; return i; }
__device__ __forceinline__ int clampi(int i, int lo, int hi){ return i < lo ? lo : (i > hi ? hi : i); }

// ---------------- init per-image stats ----------------
// stats[img*4+0] = min edge-density bits, stats[img*4+1] = max edge-density bits
// stats[img*4+2] = min sparsity bits,     stats[img*4+3] = max sparsity bits
__global__ void k_init(uint32_t* stats){
  int i = threadIdx.x;
  if (i < NB){ stats[i*4+0] = 0x7F7FFFFFu; stats[i*4+1] = 0u; stats[i*4+2] = 0u; stats[i*4+3] = 0u; }
}

// ---------------- denorm + gray + quantized bins + histogram ----------------
__global__ void k_prep(const float* __restrict__ x, const float* __restrict__ mean,
                       const float* __restrict__ stdv, float* __restrict__ gray,
                       uint16_t* __restrict__ comb, uint32_t* __restrict__ hist)
{
#pragma clang fp contract(off)
  __shared__ uint32_t h[NBINS];
  for (int i = threadIdx.x; i < NBINS; i += blockDim.x) h[i] = 0u;
  __syncthreads();
  int img  = blockIdx.x >> 4;
  int base = (blockIdx.x & 15) * 16384;
  float m0 = mean[0], m1 = mean[1], m2 = mean[2];
  float s0 = stdv[0], s1 = stdv[1], s2 = stdv[2];
  const float* xb = x + (size_t)img * 3 * HW;
  for (int i = threadIdx.x; i < 16384; i += blockDim.x){
    int p = base + i;
    float xr = clip01(xb[p]        * s0 + m0);
    float xg = clip01(xb[HW + p]   * s1 + m1);
    float xbl= clip01(xb[2*HW + p] * s2 + m2);
    float gy = 0.299f*xr + 0.587f*xg + 0.114f*xbl;
    gray[(size_t)img*HW + p] = gy;
    int c = ((int)rintf(xr*15.0f))*256 + ((int)rintf(xg*15.0f))*16 + (int)rintf(xbl*15.0f);
    comb[(size_t)img*HW + p] = (uint16_t)c;
    atomicAdd(&h[c], 1u);
  }
  __syncthreads();
  uint32_t* gh = hist + img * NBINS;
  for (int i = threadIdx.x; i < NBINS; i += blockDim.x){ uint32_t v = h[i]; if (v) atomicAdd(&gh[i], v); }
}

// ---------------- sparsity min/max from histogram ----------------
__global__ void k_spb(const uint32_t* __restrict__ hist, uint32_t* __restrict__ stats){
  int img = blockIdx.x;
  uint32_t mx = 0u, mn = 0xFFFFFFFFu;
  for (int i = threadIdx.x; i < NBINS; i += 256){
    uint32_t c = hist[img*NBINS + i];
    if (c > mx) mx = c;
    if (c > 0u && c < mn) mn = c;
  }
  __shared__ uint32_t rmx[256], rmn[256];
  rmx[threadIdx.x] = mx; rmn[threadIdx.x] = mn;
  __syncthreads();
  for (int s = 128; s > 0; s >>= 1){
    if (threadIdx.x < (unsigned)s){
      rmx[threadIdx.x] = max(rmx[threadIdx.x], rmx[threadIdx.x + s]);
      rmn[threadIdx.x] = min(rmn[threadIdx.x], rmn[threadIdx.x + s]);
    }
    __syncthreads();
  }
  if (threadIdx.x == 0){
    float sp_min = -logf((float)rmx[0] / 262144.0f + 1e-9f);   // most frequent bin
    float sp_max = -logf((float)rmn[0] / 262144.0f + 1e-9f);   // rarest occupied bin
    stats[img*4+2] = __float_as_uint(sp_min);
    stats[img*4+3] = __float_as_uint(sp_max);
  }
}

// ---------------- 5x5 Gaussian blur (sigma=1), reflect pad ----------------
__global__ void k_blur5(const float* __restrict__ gray, float* __restrict__ out)
{
#pragma clang fp contract(off)
  int idx = blockIdx.x * 256 + threadIdx.x;
  int img = idx >> 18;
  int p   = idx & (HW - 1);
  int y = p >> 9, xc = p & 511;
  float g[5]; float s = 0.0f;
  for (int i = 0; i < 5; i++){ float t = (float)i - 2.0f; g[i] = expf(-(t*t)/2.0f); s += g[i]; }
  for (int i = 0; i < 5; i++) g[i] /= s;
  const float* gb = gray + (size_t)img*HW;
  float acc = 0.0f;
  for (int ky = 0; ky < 5; ky++){
    int yy = refl(y + ky - 2, HH);
    const float* row = gb + yy*WW;
    for (int kx = 0; kx < 5; kx++){
      int xx = refl(xc + kx - 2, WW);
      acc += (g[ky]*g[kx]) * row[xx];
    }
  }
  out[idx] = acc;
}

// ---------------- Sobel (edge/replicate pad) -> mag + direction ----------------
__global__ void k_sobel(const float* __restrict__ blur, float* __restrict__ mag, uint8_t* __restrict__ dir)
{
#pragma clang fp contract(off)
  int idx = blockIdx.x * 256 + threadIdx.x;
  int img = idx >> 18;
  int p   = idx & (HW - 1);
  int y = p >> 9, xc = p & 511;
  const float* b = blur + (size_t)img*HW;
  float v[3][3];
  for (int dy = 0; dy < 3; dy++){
    int yy = clampi(y + dy - 1, 0, HH-1);
    for (int dx = 0; dx < 3; dx++){
      int xx = clampi(xc + dx - 1, 0, WW-1);
      v[dy][dx] = b[yy*WW + xx];
    }
  }
  float gx = (v[0][2] - v[0][0]) + 2.0f*(v[1][2] - v[1][0]) + (v[2][2] - v[2][0]);
  float gy = (v[2][0] + 2.0f*v[2][1] + v[2][2]) - (v[0][0] + 2.0f*v[0][1] + v[0][2]);
  float m = sqrtf(gx*gx + gy*gy + 1e-6f);
  float ang = atan2f(gy, gx) * 57.29577951308232f;
  int ai = (int)rintf(ang / 45.0f);           // [-4,4], round-half-even like jnp.round
  mag[idx] = m;
  dir[idx] = (uint8_t)(ai & 7);
}

// ---------------- NMS + double threshold -> bitmasks (weak, strong) ----------------
__global__ void k_nms(const float* __restrict__ mag, const uint8_t* __restrict__ dir,
                      unsigned long long* __restrict__ A, unsigned long long* __restrict__ S)
{
  int idx = blockIdx.x * 256 + threadIdx.x;
  int img = idx >> 18;
  int p   = idx & (HW - 1);
  int y = p >> 9, xc = p & 511;
  const float* mb = mag + (size_t)img*HW;
  float m = mb[p];
  int d  = dir[idx];
  int d2 = (d + 4) & 7;
  const int OY[8] = {0,1,1,1,0,-1,-1,-1};
  const int OX[8] = {1,1,0,-1,-1,-1,0,1};
  float mp = 0.0f, mn = 0.0f;
  { int yy = y + OY[d],  xx = xc + OX[d];  if (yy>=0 && yy<HH && xx>=0 && xx<WW) mp = mb[yy*WW+xx]; }
  { int yy = y + OY[d2], xx = xc + OX[d2]; if (yy>=0 && yy<HH && xx>=0 && xx<WW) mn = mb[yy*WW+xx]; }
  bool keep = ((m - mp) > 0.0f) && ((m - mn) > 0.0f);
  float mf = keep ? m : 0.0f;
  bool strong = mf > 0.2f;
  bool weak   = (mf > 0.1f) && !(mf > 0.2f);
  unsigned long long wb = __ballot(weak);
  unsigned long long sb = __ballot(strong);
  if ((threadIdx.x & 63) == 0){ A[idx >> 6] = wb; S[idx >> 6] = sb; }
}

// ---------------- hysteresis fixpoint on bitmasks, one block per image ----------------
__device__ __forceinline__ bool hyst_update(unsigned long long (*sS)[8],
                                            const unsigned long long (*sP)[8],
                                            int r, int w)
{
  unsigned long long P = sP[r][w];
  if (!P) return false;
  unsigned long long Sv = sS[r][w];
  unsigned long long nb = 0ull;
  #pragma unroll
  for (int k = 0; k < 3; k++){
    int rr = r + k - 1;
    if (rr < 0 || rr >= HH) continue;
    unsigned long long xm = sS[rr][w];
    unsigned long long xl = (w > 0) ? sS[rr][w-1] : 0ull;
    unsigned long long xr = (w < 7) ? sS[rr][w+1] : 0ull;
    nb |= xm | (xm << 1) | (xl >> 63) | (xm >> 1) | (xr << 63);
  }
  unsigned long long g = Sv | (P & nb);
  if (g == Sv) return false;
  // Kogge-Stone masked flood within the 64-bit word, both directions
  unsigned long long p1 = P, g1 = g;
  g1 |= p1 & (g1 << 1);  p1 &= (p1 << 1);
  g1 |= p1 & (g1 << 2);  p1 &= (p1 << 2);
  g1 |= p1 & (g1 << 4);  p1 &= (p1 << 4);
  g1 |= p1 & (g1 << 8);  p1 &= (p1 << 8);
  g1 |= p1 & (g1 << 16); p1 &= (p1 << 16);
  g1 |= p1 & (g1 << 32);
  unsigned long long p2 = P, g2 = g;
  g2 |= p2 & (g2 >> 1);  p2 &= (p2 >> 1);
  g2 |= p2 & (g2 >> 2);  p2 &= (p2 >> 2);
  g2 |= p2 & (g2 >> 4);  p2 &= (p2 >> 4);
  g2 |= p2 & (g2 >> 8);  p2 &= (p2 >> 8);
  g2 |= p2 & (g2 >> 16); p2 &= (p2 >> 16);
  g2 |= p2 & (g2 >> 32);
  unsigned long long ns = g1 | g2;
  if (ns != Sv){ sS[r][w] = ns; return true; }
  return false;
}

__global__ void __launch_bounds__(512) k_hyst(const unsigned long long* __restrict__ A,
                                              unsigned long long* __restrict__ S)
{
  __shared__ unsigned long long sS[HH][8];   // 32 KiB
  __shared__ unsigned long long sP[HH][8];   // 32 KiB
  int img = blockIdx.x;
  const unsigned long long* gA = A + img * 4096;
  unsigned long long*       gS = S + img * 4096;
  for (int i = threadIdx.x; i < 4096; i += 512){
    unsigned long long sv = gS[i];
    sS[i >> 3][i & 7] = sv;
    sP[i >> 3][i & 7] = gA[i] | sv;     // propagate mask = weak | strong
  }
  __syncthreads();
  int w  = threadIdx.x & 7;
  int r0 = (threadIdx.x >> 3) << 3;     // 8 rows per thread
  for (;;){
    bool c = false;
    for (int r = r0;     r < r0 + 8; r++) c |= hyst_update(sS, sP, r, w);
    for (int r = r0 + 7; r >= r0;    r--) c |= hyst_update(sS, sP, r, w);
    if (!__syncthreads_or(c ? 1 : 0)) break;
  }
  for (int i = threadIdx.x; i < 4096; i += 512) gS[i] = sS[i >> 3][i & 7];
}

// ---------------- bits -> float edges ----------------
__global__ void k_b2f(const unsigned long long* __restrict__ S, float* __restrict__ out){
  int idx = blockIdx.x * 256 + threadIdx.x;
  out[idx] = (float)((S[idx >> 6] >> (idx & 63)) & 1ull);
}

// ---------------- 11-tap Gaussian (sigma=1.5), separable, reflect pad ----------------
__global__ void k_b11h(const float* __restrict__ in, float* __restrict__ out)
{
#pragma clang fp contract(off)
  int idx = blockIdx.x * 256 + threadIdx.x;
  int img = idx >> 18;
  int p   = idx & (HW - 1);
  int y = p >> 9, xc = p & 511;
  float g[11]; float s = 0.0f;
  for (int i = 0; i < 11; i++){ float t = (float)i - 5.0f; g[i] = expf(-(t*t)/4.5f); s += g[i]; }
  for (int i = 0; i < 11; i++) g[i] /= s;
  const float* row = in + (size_t)img*HW + y*WW;
  float acc = 0.0f;
  for (int k = 0; k < 11; k++){ int xx = refl(xc + k - 5, WW); acc += g[k] * row[xx]; }
  out[idx] = acc;
}

// vertical pass; per-block (min,max) partials -> part[] (no global atomics)
__global__ void k_b11v(const float* __restrict__ in, float* __restrict__ out, float2* __restrict__ part)
{
#pragma clang fp contract(off)
  int idx = blockIdx.x * 256 + threadIdx.x;
  int img = idx >> 18;
  int p   = idx & (HW - 1);
  int y = p >> 9, xc = p & 511;
  float g[11]; float s = 0.0f;
  for (int i = 0; i < 11; i++){ float t = (float)i - 5.0f; g[i] = expf(-(t*t)/4.5f); s += g[i]; }
  for (int i = 0; i < 11; i++) g[i] /= s;
  const float* ib = in + (size_t)img*HW;
  float acc = 0.0f;
  for (int k = 0; k < 11; k++){ int yy = refl(y + k - 5, HH); acc += g[k] * ib[yy*WW + xc]; }
  out[idx] = acc;
  float mn = acc, mx = acc;
  for (int off = 32; off >= 1; off >>= 1){
    mn = fminf(mn, __shfl_down(mn, off));
    mx = fmaxf(mx, __shfl_down(mx, off));
  }
  __shared__ float smn[4], smx[4];
  int wv = threadIdx.x >> 6, ln = threadIdx.x & 63;
  if (ln == 0){ smn[wv] = mn; smx[wv] = mx; }
  __syncthreads();
  if (threadIdx.x == 0){
    float a = fminf(fminf(smn[0], smn[1]), fminf(smn[2], smn[3]));
    float b = fmaxf(fmaxf(smx[0], smx[1]), fmaxf(smx[2], smx[3]));
    part[blockIdx.x] = make_float2(a, b);
  }
}

// reduce 1024 per-block partials per image -> stats (one block per image)
__global__ void k_edred(const float2* __restrict__ part, uint32_t* __restrict__ stats){
  int img = blockIdx.x;
  const float2* pp = part + img * 1024;
  float mn =  3.4e38f, mx = -3.4e38f;
  for (int i = threadIdx.x; i < 1024; i += 256){
    float2 v = pp[i];
    mn = fminf(mn, v.x); mx = fmaxf(mx, v.y);
  }
  for (int off = 32; off >= 1; off >>= 1){
    mn = fminf(mn, __shfl_down(mn, off));
    mx = fmaxf(mx, __shfl_down(mx, off));
  }
  __shared__ float smn[4], smx[4];
  int wv = threadIdx.x >> 6, ln = threadIdx.x & 63;
  if (ln == 0){ smn[wv] = mn; smx[wv] = mx; }
  __syncthreads();
  if (threadIdx.x == 0){
    float a = fminf(fminf(smn[0], smn[1]), fminf(smn[2], smn[3]));
    float b = fmaxf(fmaxf(smx[0], smx[1]), fmaxf(smx[2], smx[3]));
    stats[img*4+0] = __float_as_uint(a);
    stats[img*4+1] = __float_as_uint(b);
  }
}

// ---------------- fuse: normalize both maps, sigmoid ----------------
__global__ void k_final(const float* __restrict__ ed, const uint16_t* __restrict__ comb,
                        const uint32_t* __restrict__ hist, const uint32_t* __restrict__ stats,
                        const float* __restrict__ alpha, const float* __restrict__ beta,
                        float* __restrict__ out)
{
#pragma clang fp contract(off)
  int idx = blockIdx.x * 256 + threadIdx.x;
  int img = idx >> 18;
  float a = alpha[0], b = beta[0];
  float mne = __uint_as_float(stats[img*4+0]);
  float mxe = __uint_as_float(stats[img*4+1]);
  float mns = __uint_as_float(stats[img*4+2]);
  float mxs = __uint_as_float(stats[img*4+3]);
  float e  = ed[idx];
  float sp = -logf((float)hist[img*NBINS + comb[idx]] / 262144.0f + 1e-9f);
  float en = (e  - mne) / (mxe - mne + 1e-9f);
  float sn = (sp - mns) / (mxs - mns + 1e-9f);
  float f  = a*en + b*sn;
  out[idx] = 1.0f / (1.0f + expf(-f));
}

extern "C" void kernel_launch(void* const* d_in, const int* in_sizes, int n_in,
                              void* d_out, int out_size, void* d_ws, size_t ws_size,
                              hipStream_t stream)
{
  const float* x     = (const float*)d_in[0];
  const float* mean  = (const float*)d_in[1];
  const float* stdv  = (const float*)d_in[2];
  const float* alpha = (const float*)d_in[3];
  const float* beta  = (const float*)d_in[4];
  float* out = (float*)d_out;

  char* ws = (char*)d_ws;
  float*              buf0  = (float*)ws;                                   // 16 MB (gray -> mag -> tmp11)
  uint16_t*           comb  = (uint16_t*)(ws + (16u << 20));                // 8 MB
  uint8_t*            dir   = (uint8_t*)(ws + (24u << 20));                 // 4 MB (dead after k_nms)
  float2*             part  = (float2*)(ws + (24u << 20));                  // aliases dir: 128 KB, used after k_nms
  uint32_t*           hist  = (uint32_t*)(ws + (28u << 20));                // 256 KB
  unsigned long long* Ab    = (unsigned long long*)(ws + (28u << 20) + (1u << 18));               // 512 KB
  unsigned long long* Sb    = (unsigned long long*)(ws + (28u << 20) + (1u << 18) + (1u << 19));  // 512 KB
  uint32_t*           stats = (uint32_t*)(ws + (28u << 20) + (1u << 18) + (2u << 19));            // 256 B

  hipMemsetAsync(hist, 0, NB * NBINS * sizeof(uint32_t), stream);
  hipLaunchKernelGGL(k_init, dim3(1), dim3(64), 0, stream, stats);
  hipLaunchKernelGGL(k_prep, dim3(256), dim3(256), 0, stream, x, mean, stdv, buf0, comb, hist);
  hipLaunchKernelGGL(k_spb,  dim3(NB), dim3(256), 0, stream, hist, stats);
  hipLaunchKernelGGL(k_blur5, dim3(16384), dim3(256), 0, stream, buf0, out);         // blurred -> d_out
  hipLaunchKernelGGL(k_sobel, dim3(16384), dim3(256), 0, stream, out, buf0, dir);    // mag -> buf0
  hipLaunchKernelGGL(k_nms,   dim3(16384), dim3(256), 0, stream, buf0, dir, Ab, Sb);
  hipLaunchKernelGGL(k_hyst,  dim3(NB), dim3(512), 0, stream, Ab, Sb);
  hipLaunchKernelGGL(k_b2f,   dim3(16384), dim3(256), 0, stream, Sb, out);           // edges -> d_out
  hipLaunchKernelGGL(k_b11h,  dim3(16384), dim3(256), 0, stream, out, buf0);         // tmp -> buf0
  hipLaunchKernelGGL(k_b11v,  dim3(16384), dim3(256), 0, stream, buf0, out, part);   // density -> d_out
  hipLaunchKernelGGL(k_edred, dim3(NB), dim3(256), 0, stream, part, stats);
  hipLaunchKernelGGL(k_final, dim3(16384), dim3(256), 0, stream, out, comb, hist, stats, alpha, beta, out);
}

// Round 3
// 190.749 us; speedup vs baseline: 2.0663x; 1.0003x over previous
//
#include <hip/hip_runtime.h>
#include <stdint.h>

#define NB 16
#define HH 512
#define WW 512
#define HW (HH*WW)          // 262144
#define NBINS 4096

__device__ __forceinline__ float clip01(float v){ return fminf(fmaxf(v, 0.0f), 1.0f); }
__device__ __forceinline__ int refl(int i, int n){ if (i < 0) i = -i; if (i >= n) i = 2*n - 2 - i; return i; }
__device__ __forceinline__ int clampi(int i, int lo, int hi){ return i < lo ? lo : (i > hi ? hi : i); }

// ---------------- init per-image stats ----------------
__global__ void k_init(uint32_t* stats){
  int i = threadIdx.x;
  if (i < NB){ stats[i*4+0] = 0x7F7FFFFFu; stats[i*4+1] = 0u; stats[i*4+2] = 0u; stats[i*4+3] = 0u; }
}

// ---------------- denorm + gray + quantized bins + histogram (vectorized) ----------------
// grid: 16 img x 64 chunks = 1024 blocks, 256 threads; 4096 px per block; 16 px/thread via float4
__global__ void k_prep(const float* __restrict__ x, const float* __restrict__ mean,
                       const float* __restrict__ stdv, float* __restrict__ gray,
                       uint16_t* __restrict__ comb, uint32_t* __restrict__ hist)
{
#pragma clang fp contract(off)
  __shared__ uint32_t h[NBINS];
  for (int i = threadIdx.x; i < NBINS; i += 256) h[i] = 0u;
  __syncthreads();
  int img  = blockIdx.x >> 6;
  int base = (blockIdx.x & 63) * 4096;          // pixel base within image
  float m0 = mean[0], m1 = mean[1], m2 = mean[2];
  float s0 = stdv[0], s1 = stdv[1], s2 = stdv[2];
  const float* xb = x + (size_t)img * 3 * HW;
  float*     gb   = gray + (size_t)img*HW;
  uint16_t*  cb   = comb + (size_t)img*HW;
  #pragma unroll
  for (int it = 0; it < 4; it++){
    int f4 = it*256 + threadIdx.x;              // float4 index within chunk: 0..1023
    int p  = base + f4*4;
    float4 r = *(const float4*)(xb + p);
    float4 g = *(const float4*)(xb + HW + p);
    float4 b = *(const float4*)(xb + 2*HW + p);
    float xr[4] = {r.x, r.y, r.z, r.w};
    float xg[4] = {g.x, g.y, g.z, g.w};
    float xbl[4] = {b.x, b.y, b.z, b.w};
    float gy[4]; uint16_t cc[4];
    #pragma unroll
    for (int j = 0; j < 4; j++){
      float cr = clip01(xr[j]*s0 + m0);
      float cg = clip01(xg[j]*s1 + m1);
      float cbv= clip01(xbl[j]*s2 + m2);
      gy[j] = 0.299f*cr + 0.587f*cg + 0.114f*cbv;
      int c = ((int)rintf(cr*15.0f))*256 + ((int)rintf(cg*15.0f))*16 + (int)rintf(cbv*15.0f);
      cc[j] = (uint16_t)c;
      atomicAdd(&h[c], 1u);
    }
    *(float4*)(gb + p) = make_float4(gy[0], gy[1], gy[2], gy[3]);
    ushort4 cv; cv.x = cc[0]; cv.y = cc[1]; cv.z = cc[2]; cv.w = cc[3];
    *(ushort4*)(cb + p) = cv;
  }
  __syncthreads();
  uint32_t* gh = hist + img * NBINS;
  for (int i = threadIdx.x; i < NBINS; i += 256){ uint32_t v = h[i]; if (v) atomicAdd(&gh[i], v); }
}

// ---------------- sparsity min/max from histogram ----------------
__global__ void k_spb(const uint32_t* __restrict__ hist, uint32_t* __restrict__ stats){
  int img = blockIdx.x;
  uint32_t mx = 0u, mn = 0xFFFFFFFFu;
  for (int i = threadIdx.x; i < NBINS; i += 256){
    uint32_t c = hist[img*NBINS + i];
    if (c > mx) mx = c;
    if (c > 0u && c < mn) mn = c;
  }
  __shared__ uint32_t rmx[256], rmn[256];
  rmx[threadIdx.x] = mx; rmn[threadIdx.x] = mn;
  __syncthreads();
  for (int s = 128; s > 0; s >>= 1){
    if (threadIdx.x < (unsigned)s){
      rmx[threadIdx.x] = max(rmx[threadIdx.x], rmx[threadIdx.x + s]);
      rmn[threadIdx.x] = min(rmn[threadIdx.x], rmn[threadIdx.x + s]);
    }
    __syncthreads();
  }
  if (threadIdx.x == 0){
    float sp_min = -logf((float)rmx[0] / 262144.0f + 1e-9f);
    float sp_max = -logf((float)rmn[0] / 262144.0f + 1e-9f);
    stats[img*4+2] = __float_as_uint(sp_min);
    stats[img*4+3] = __float_as_uint(sp_max);
  }
}

// ---------------- 5x5 Gaussian blur (sigma=1), reflect pad ----------------
__global__ void k_blur5(const float* __restrict__ gray, float* __restrict__ out)
{
#pragma clang fp contract(off)
  int idx = blockIdx.x * 256 + threadIdx.x;
  int img = idx >> 18;
  int p   = idx & (HW - 1);
  int y = p >> 9, xc = p & 511;
  float g[5]; float s = 0.0f;
  for (int i = 0; i < 5; i++){ float t = (float)i - 2.0f; g[i] = expf(-(t*t)/2.0f); s += g[i]; }
  for (int i = 0; i < 5; i++) g[i] /= s;
  const float* gb = gray + (size_t)img*HW;
  float acc = 0.0f;
  for (int ky = 0; ky < 5; ky++){
    int yy = refl(y + ky - 2, HH);
    const float* row = gb + yy*WW;
    for (int kx = 0; kx < 5; kx++){
      int xx = refl(xc + kx - 2, WW);
      acc += (g[ky]*g[kx]) * row[xx];
    }
  }
  out[idx] = acc;
}

// ---------------- Sobel (edge/replicate pad) -> mag + direction ----------------
__global__ void k_sobel(const float* __restrict__ blur, float* __restrict__ mag, uint8_t* __restrict__ dir)
{
#pragma clang fp contract(off)
  int idx = blockIdx.x * 256 + threadIdx.x;
  int img = idx >> 18;
  int p   = idx & (HW - 1);
  int y = p >> 9, xc = p & 511;
  const float* b = blur + (size_t)img*HW;
  float v[3][3];
  for (int dy = 0; dy < 3; dy++){
    int yy = clampi(y + dy - 1, 0, HH-1);
    for (int dx = 0; dx < 3; dx++){
      int xx = clampi(xc + dx - 1, 0, WW-1);
      v[dy][dx] = b[yy*WW + xx];
    }
  }
  float gx = (v[0][2] - v[0][0]) + 2.0f*(v[1][2] - v[1][0]) + (v[2][2] - v[2][0]);
  float gy = (v[2][0] + 2.0f*v[2][1] + v[2][2]) - (v[0][0] + 2.0f*v[0][1] + v[0][2]);
  float m = sqrtf(gx*gx + gy*gy + 1e-6f);
  float ang = atan2f(gy, gx) * 57.29577951308232f;
  int ai = (int)rintf(ang / 45.0f);
  mag[idx] = m;
  dir[idx] = (uint8_t)(ai & 7);
}

// ---------------- NMS + double threshold -> bitmasks (weak, strong) ----------------
__global__ void k_nms(const float* __restrict__ mag, const uint8_t* __restrict__ dir,
                      unsigned long long* __restrict__ A, unsigned long long* __restrict__ S)
{
  int idx = blockIdx.x * 256 + threadIdx.x;
  int img = idx >> 18;
  int p   = idx & (HW - 1);
  int y = p >> 9, xc = p & 511;
  const float* mb = mag + (size_t)img*HW;
  float m = mb[p];
  int d  = dir[idx];
  int d2 = (d + 4) & 7;
  const int OY[8] = {0,1,1,1,0,-1,-1,-1};
  const int OX[8] = {1,1,0,-1,-1,-1,0,1};
  float mp = 0.0f, mn = 0.0f;
  { int yy = y + OY[d],  xx = xc + OX[d];  if (yy>=0 && yy<HH && xx>=0 && xx<WW) mp = mb[yy*WW+xx]; }
  { int yy = y + OY[d2], xx = xc + OX[d2]; if (yy>=0 && yy<HH && xx>=0 && xx<WW) mn = mb[yy*WW+xx]; }
  bool keep = ((m - mp) > 0.0f) && ((m - mn) > 0.0f);
  float mf = keep ? m : 0.0f;
  bool strong = mf > 0.2f;
  bool weak   = (mf > 0.1f) && !(mf > 0.2f);
  unsigned long long wb = __ballot(weak);
  unsigned long long sb = __ballot(strong);
  if ((threadIdx.x & 63) == 0){ A[idx >> 6] = wb; S[idx >> 6] = sb; }
}

// ---------------- hysteresis fixpoint on bitmasks, one block per image ----------------
__device__ __forceinline__ bool hyst_update(unsigned long long (*sS)[8],
                                            const unsigned long long (*sP)[8],
                                            int r, int w)
{
  unsigned long long P = sP[r][w];
  if (!P) return false;
  unsigned long long Sv = sS[r][w];
  unsigned long long nb = 0ull;
  #pragma unroll
  for (int k = 0; k < 3; k++){
    int rr = r + k - 1;
    if (rr < 0 || rr >= HH) continue;
    unsigned long long xm = sS[rr][w];
    unsigned long long xl = (w > 0) ? sS[rr][w-1] : 0ull;
    unsigned long long xr = (w < 7) ? sS[rr][w+1] : 0ull;
    nb |= xm | (xm << 1) | (xl >> 63) | (xm >> 1) | (xr << 63);
  }
  unsigned long long g = Sv | (P & nb);
  if (g == Sv) return false;
  unsigned long long p1 = P, g1 = g;
  g1 |= p1 & (g1 << 1);  p1 &= (p1 << 1);
  g1 |= p1 & (g1 << 2);  p1 &= (p1 << 2);
  g1 |= p1 & (g1 << 4);  p1 &= (p1 << 4);
  g1 |= p1 & (g1 << 8);  p1 &= (p1 << 8);
  g1 |= p1 & (g1 << 16); p1 &= (p1 << 16);
  g1 |= p1 & (g1 << 32);
  unsigned long long p2 = P, g2 = g;
  g2 |= p2 & (g2 >> 1);  p2 &= (p2 >> 1);
  g2 |= p2 & (g2 >> 2);  p2 &= (p2 >> 2);
  g2 |= p2 & (g2 >> 4);  p2 &= (p2 >> 4);
  g2 |= p2 & (g2 >> 8);  p2 &= (p2 >> 8);
  g2 |= p2 & (g2 >> 16); p2 &= (p2 >> 16);
  g2 |= p2 & (g2 >> 32);
  unsigned long long ns = g1 | g2;
  if (ns != Sv){ sS[r][w] = ns; return true; }
  return false;
}

__global__ void __launch_bounds__(512) k_hyst(const unsigned long long* __restrict__ A,
                                              unsigned long long* __restrict__ S)
{
  __shared__ unsigned long long sS[HH][8];   // 32 KiB
  __shared__ unsigned long long sP[HH][8];   // 32 KiB
  int img = blockIdx.x;
  const unsigned long long* gA = A + img * 4096;
  unsigned long long*       gS = S + img * 4096;
  for (int i = threadIdx.x; i < 4096; i += 512){
    unsigned long long sv = gS[i];
    sS[i >> 3][i & 7] = sv;
    sP[i >> 3][i & 7] = gA[i] | sv;
  }
  __syncthreads();
  int w  = threadIdx.x & 7;
  int r0 = (threadIdx.x >> 3) << 3;
  for (;;){
    bool c = false;
    for (int r = r0;     r < r0 + 8; r++) c |= hyst_update(sS, sP, r, w);
    for (int r = r0 + 7; r >= r0;    r--) c |= hyst_update(sS, sP, r, w);
    if (!__syncthreads_or(c ? 1 : 0)) break;
  }
  for (int i = threadIdx.x; i < 4096; i += 512) gS[i] = sS[i >> 3][i & 7];
}

// ---------------- 11-tap horizontal Gaussian directly from edge bitmask ----------------
// edge values are exactly 0/1 so g[k]*bit is bit-identical to the float path
__global__ void k_b11h(const unsigned long long* __restrict__ S, float* __restrict__ out)
{
#pragma clang fp contract(off)
  int idx = blockIdx.x * 256 + threadIdx.x;
  int img = idx >> 18;
  int p   = idx & (HW - 1);
  int y = p >> 9, xc = p & 511;
  float g[11]; float s = 0.0f;
  for (int i = 0; i < 11; i++){ float t = (float)i - 5.0f; g[i] = expf(-(t*t)/4.5f); s += g[i]; }
  for (int i = 0; i < 11; i++) g[i] /= s;
  const unsigned long long* row = S + img*4096 + y*8;
  float acc = 0.0f;
  for (int k = 0; k < 11; k++){
    int xx = refl(xc + k - 5, WW);
    float bv = (float)((row[xx >> 6] >> (xx & 63)) & 1ull);
    acc += g[k] * bv;
  }
  out[idx] = acc;
}

// vertical pass; per-block (min,max) partials -> part[] (no global atomics)
__global__ void k_b11v(const float* __restrict__ in, float* __restrict__ out, float2* __restrict__ part)
{
#pragma clang fp contract(off)
  int idx = blockIdx.x * 256 + threadIdx.x;
  int img = idx >> 18;
  int p   = idx & (HW - 1);
  int y = p >> 9, xc = p & 511;
  float g[11]; float s = 0.0f;
  for (int i = 0; i < 11; i++){ float t = (float)i - 5.0f; g[i] = expf(-(t*t)/4.5f); s += g[i]; }
  for (int i = 0; i < 11; i++) g[i] /= s;
  const float* ib = in + (size_t)img*HW;
  float acc = 0.0f;
  for (int k = 0; k < 11; k++){ int yy = refl(y + k - 5, HH); acc += g[k] * ib[yy*WW + xc]; }
  out[idx] = acc;
  float mn = acc, mx = acc;
  for (int off = 32; off >= 1; off >>= 1){
    mn = fminf(mn, __shfl_down(mn, off));
    mx = fmaxf(mx, __shfl_down(mx, off));
  }
  __shared__ float smn[4], smx[4];
  int wv = threadIdx.x >> 6, ln = threadIdx.x & 63;
  if (ln == 0){ smn[wv] = mn; smx[wv] = mx; }
  __syncthreads();
  if (threadIdx.x == 0){
    float a = fminf(fminf(smn[0], smn[1]), fminf(smn[2], smn[3]));
    float b = fmaxf(fmaxf(smx[0], smx[1]), fmaxf(smx[2], smx[3]));
    part[blockIdx.x] = make_float2(a, b);
  }
}

// reduce 1024 per-block partials per image -> stats
__global__ void k_edred(const float2* __restrict__ part, uint32_t* __restrict__ stats){
  int img = blockIdx.x;
  const float2* pp = part + img * 1024;
  float mn =  3.4e38f, mx = -3.4e38f;
  for (int i = threadIdx.x; i < 1024; i += 256){
    float2 v = pp[i];
    mn = fminf(mn, v.x); mx = fmaxf(mx, v.y);
  }
  for (int off = 32; off >= 1; off >>= 1){
    mn = fminf(mn, __shfl_down(mn, off));
    mx = fmaxf(mx, __shfl_down(mx, off));
  }
  __shared__ float smn[4], smx[4];
  int wv = threadIdx.x >> 6, ln = threadIdx.x & 63;
  if (ln == 0){ smn[wv] = mn; smx[wv] = mx; }
  __syncthreads();
  if (threadIdx.x == 0){
    float a = fminf(fminf(smn[0], smn[1]), fminf(smn[2], smn[3]));
    float b = fmaxf(fmaxf(smx[0], smx[1]), fmaxf(smx[2], smx[3]));
    stats[img*4+0] = __float_as_uint(a);
    stats[img*4+1] = __float_as_uint(b);
  }
}

// ---------------- fuse: normalize both maps, sigmoid ----------------
__global__ void k_final(const float* __restrict__ ed, const uint16_t* __restrict__ comb,
                        const uint32_t* __restrict__ hist, const uint32_t* __restrict__ stats,
                        const float* __restrict__ alpha, const float* __restrict__ beta,
                        float* __restrict__ out)
{
#pragma clang fp contract(off)
  int idx = blockIdx.x * 256 + threadIdx.x;
  int img = idx >> 18;
  float a = alpha[0], b = beta[0];
  float mne = __uint_as_float(stats[img*4+0]);
  float mxe = __uint_as_float(stats[img*4+1]);
  float mns = __uint_as_float(stats[img*4+2]);
  float mxs = __uint_as_float(stats[img*4+3]);
  float e  = ed[idx];
  float sp = -logf((float)hist[img*NBINS + comb[idx]] / 262144.0f + 1e-9f);
  float en = (e  - mne) / (mxe - mne + 1e-9f);
  float sn = (sp - mns) / (mxs - mns + 1e-9f);
  float f  = a*en + b*sn;
  out[idx] = 1.0f / (1.0f + expf(-f));
}

extern "C" void kernel_launch(void* const* d_in, const int* in_sizes, int n_in,
                              void* d_out, int out_size, void* d_ws, size_t ws_size,
                              hipStream_t stream)
{
  const float* x     = (const float*)d_in[0];
  const float* mean  = (const float*)d_in[1];
  const float* stdv  = (const float*)d_in[2];
  const float* alpha = (const float*)d_in[3];
  const float* beta  = (const float*)d_in[4];
  float* out = (float*)d_out;

  char* ws = (char*)d_ws;
  float*              buf0  = (float*)ws;                                   // 16 MB (gray -> mag -> tmp11)
  uint16_t*           comb  = (uint16_t*)(ws + (16u << 20));                // 8 MB
  uint8_t*            dir   = (uint8_t*)(ws + (24u << 20));                 // 4 MB (dead after k_nms)
  float2*             part  = (float2*)(ws + (24u << 20));                  // aliases dir
  uint32_t*           hist  = (uint32_t*)(ws + (28u << 20));                // 256 KB
  unsigned long long* Ab    = (unsigned long long*)(ws + (28u << 20) + (1u << 18));               // 512 KB
  unsigned long long* Sb    = (unsigned long long*)(ws + (28u << 20) + (1u << 18) + (1u << 19));  // 512 KB
  uint32_t*           stats = (uint32_t*)(ws + (28u << 20) + (1u << 18) + (2u << 19));            // 256 B

  hipMemsetAsync(hist, 0, NB * NBINS * sizeof(uint32_t), stream);
  hipLaunchKernelGGL(k_init, dim3(1), dim3(64), 0, stream, stats);
  hipLaunchKernelGGL(k_prep, dim3(1024), dim3(256), 0, stream, x, mean, stdv, buf0, comb, hist);
  hipLaunchKernelGGL(k_spb,  dim3(NB), dim3(256), 0, stream, hist, stats);
  hipLaunchKernelGGL(k_blur5, dim3(16384), dim3(256), 0, stream, buf0, out);         // blurred -> d_out
  hipLaunchKernelGGL(k_sobel, dim3(16384), dim3(256), 0, stream, out, buf0, dir);    // mag -> buf0
  hipLaunchKernelGGL(k_nms,   dim3(16384), dim3(256), 0, stream, buf0, dir, Ab, Sb);
  hipLaunchKernelGGL(k_hyst,  dim3(NB), dim3(512), 0, stream, Ab, Sb);
  hipLaunchKernelGGL(k_b11h,  dim3(16384), dim3(256), 0, stream, Sb, buf0);          // tmp -> buf0
  hipLaunchKernelGGL(k_b11v,  dim3(16384), dim3(256), 0, stream, buf0, out, part);   // density -> d_out
  hipLaunchKernelGGL(k_edred, dim3(NB), dim3(256), 0, stream, part, stats);
  hipLaunchKernelGGL(k_final, dim3(16384), dim3(256), 0, stream, out, comb, hist, stats, alpha, beta, out);
}

// Round 4
// 186.545 us; speedup vs baseline: 2.1128x; 1.0225x over previous
//
#include <hip/hip_runtime.h>
#include <stdint.h>

#define NB 16
#define HH 512
#define WW 512
#define HW (HH*WW)          // 262144
#define NBINS 4096

typedef unsigned long long u64;

__device__ __forceinline__ float clip01(float v){ return fminf(fmaxf(v, 0.0f), 1.0f); }
__device__ __forceinline__ int refl(int i, int n){ if (i < 0) i = -i; if (i >= n) i = 2*n - 2 - i; return i; }
__device__ __forceinline__ int clampi(int i, int lo, int hi){ return i < lo ? lo : (i > hi ? hi : i); }

// ---------------- denorm + gray + quantized bins + histogram (vectorized) ----------------
__global__ void k_prep(const float* __restrict__ x, const float* __restrict__ mean,
                       const float* __restrict__ stdv, float* __restrict__ gray,
                       uint16_t* __restrict__ comb, uint32_t* __restrict__ hist)
{
#pragma clang fp contract(off)
  __shared__ uint32_t h[NBINS];
  for (int i = threadIdx.x; i < NBINS; i += 256) h[i] = 0u;
  __syncthreads();
  int img  = blockIdx.x >> 6;
  int base = (blockIdx.x & 63) * 4096;
  float m0 = mean[0], m1 = mean[1], m2 = mean[2];
  float s0 = stdv[0], s1 = stdv[1], s2 = stdv[2];
  const float* xb = x + (size_t)img * 3 * HW;
  float*     gb   = gray + (size_t)img*HW;
  uint16_t*  cb   = comb + (size_t)img*HW;
  #pragma unroll
  for (int it = 0; it < 4; it++){
    int f4 = it*256 + threadIdx.x;
    int p  = base + f4*4;
    float4 r = *(const float4*)(xb + p);
    float4 g = *(const float4*)(xb + HW + p);
    float4 b = *(const float4*)(xb + 2*HW + p);
    float xr[4] = {r.x, r.y, r.z, r.w};
    float xg[4] = {g.x, g.y, g.z, g.w};
    float xbl[4] = {b.x, b.y, b.z, b.w};
    float gy[4]; uint16_t cc[4];
    #pragma unroll
    for (int j = 0; j < 4; j++){
      float cr = clip01(xr[j]*s0 + m0);
      float cg = clip01(xg[j]*s1 + m1);
      float cbv= clip01(xbl[j]*s2 + m2);
      gy[j] = 0.299f*cr + 0.587f*cg + 0.114f*cbv;
      int c = ((int)rintf(cr*15.0f))*256 + ((int)rintf(cg*15.0f))*16 + (int)rintf(cbv*15.0f);
      cc[j] = (uint16_t)c;
      atomicAdd(&h[c], 1u);
    }
    *(float4*)(gb + p) = make_float4(gy[0], gy[1], gy[2], gy[3]);
    ushort4 cv; cv.x = cc[0]; cv.y = cc[1]; cv.z = cc[2]; cv.w = cc[3];
    *(ushort4*)(cb + p) = cv;
  }
  __syncthreads();
  uint32_t* gh = hist + img * NBINS;
  for (int i = threadIdx.x; i < NBINS; i += 256){ uint32_t v = h[i]; if (v) atomicAdd(&gh[i], v); }
}

// ---------------- sparsity min/max from histogram ----------------
__global__ void k_spb(const uint32_t* __restrict__ hist, uint32_t* __restrict__ stats){
  int img = blockIdx.x;
  uint32_t mx = 0u, mn = 0xFFFFFFFFu;
  for (int i = threadIdx.x; i < NBINS; i += 256){
    uint32_t c = hist[img*NBINS + i];
    if (c > mx) mx = c;
    if (c > 0u && c < mn) mn = c;
  }
  __shared__ uint32_t rmx[256], rmn[256];
  rmx[threadIdx.x] = mx; rmn[threadIdx.x] = mn;
  __syncthreads();
  for (int s = 128; s > 0; s >>= 1){
    if (threadIdx.x < (unsigned)s){
      rmx[threadIdx.x] = max(rmx[threadIdx.x], rmx[threadIdx.x + s]);
      rmn[threadIdx.x] = min(rmn[threadIdx.x], rmn[threadIdx.x + s]);
    }
    __syncthreads();
  }
  if (threadIdx.x == 0){
    float sp_min = -logf((float)rmx[0] / 262144.0f + 1e-9f);
    float sp_max = -logf((float)rmn[0] / 262144.0f + 1e-9f);
    stats[img*4+2] = __float_as_uint(sp_min);
    stats[img*4+3] = __float_as_uint(sp_max);
  }
}

// ---------------- 5x5 Gaussian blur (sigma=1), reflect pad ----------------
__global__ void k_blur5(const float* __restrict__ gray, float* __restrict__ out)
{
#pragma clang fp contract(off)
  int idx = blockIdx.x * 256 + threadIdx.x;
  int img = idx >> 18;
  int p   = idx & (HW - 1);
  int y = p >> 9, xc = p & 511;
  float g[5]; float s = 0.0f;
  for (int i = 0; i < 5; i++){ float t = (float)i - 2.0f; g[i] = expf(-(t*t)/2.0f); s += g[i]; }
  for (int i = 0; i < 5; i++) g[i] /= s;
  const float* gb = gray + (size_t)img*HW;
  float acc = 0.0f;
  for (int ky = 0; ky < 5; ky++){
    int yy = refl(y + ky - 2, HH);
    const float* row = gb + yy*WW;
    for (int kx = 0; kx < 5; kx++){
      int xx = refl(xc + kx - 2, WW);
      acc += (g[ky]*g[kx]) * row[xx];
    }
  }
  out[idx] = acc;
}

// ---------------- Sobel (edge/replicate pad) -> mag + direction ----------------
__global__ void k_sobel(const float* __restrict__ blur, float* __restrict__ mag, uint8_t* __restrict__ dir)
{
#pragma clang fp contract(off)
  int idx = blockIdx.x * 256 + threadIdx.x;
  int img = idx >> 18;
  int p   = idx & (HW - 1);
  int y = p >> 9, xc = p & 511;
  const float* b = blur + (size_t)img*HW;
  float v[3][3];
  for (int dy = 0; dy < 3; dy++){
    int yy = clampi(y + dy - 1, 0, HH-1);
    for (int dx = 0; dx < 3; dx++){
      int xx = clampi(xc + dx - 1, 0, WW-1);
      v[dy][dx] = b[yy*WW + xx];
    }
  }
  float gx = (v[0][2] - v[0][0]) + 2.0f*(v[1][2] - v[1][0]) + (v[2][2] - v[2][0]);
  float gy = (v[2][0] + 2.0f*v[2][1] + v[2][2]) - (v[0][0] + 2.0f*v[0][1] + v[0][2]);
  float m = sqrtf(gx*gx + gy*gy + 1e-6f);
  float ang = atan2f(gy, gx) * 57.29577951308232f;
  int ai = (int)rintf(ang / 45.0f);
  mag[idx] = m;
  dir[idx] = (uint8_t)(ai & 7);
}

// ---------------- NMS + double threshold -> bitmasks (weak, strong) ----------------
__global__ void k_nms(const float* __restrict__ mag, const uint8_t* __restrict__ dir,
                      u64* __restrict__ A, u64* __restrict__ S)
{
  int idx = blockIdx.x * 256 + threadIdx.x;
  int img = idx >> 18;
  int p   = idx & (HW - 1);
  int y = p >> 9, xc = p & 511;
  const float* mb = mag + (size_t)img*HW;
  float m = mb[p];
  int d  = dir[idx];
  int d2 = (d + 4) & 7;
  const int OY[8] = {0,1,1,1,0,-1,-1,-1};
  const int OX[8] = {1,1,0,-1,-1,-1,0,1};
  float mp = 0.0f, mn = 0.0f;
  { int yy = y + OY[d],  xx = xc + OX[d];  if (yy>=0 && yy<HH && xx>=0 && xx<WW) mp = mb[yy*WW+xx]; }
  { int yy = y + OY[d2], xx = xc + OX[d2]; if (yy>=0 && yy<HH && xx>=0 && xx<WW) mn = mb[yy*WW+xx]; }
  bool keep = ((m - mp) > 0.0f) && ((m - mn) > 0.0f);
  float mf = keep ? m : 0.0f;
  bool strong = mf > 0.2f;
  bool weak   = (mf > 0.1f) && !(mf > 0.2f);
  u64 wb = __ballot(weak);
  u64 sb = __ballot(strong);
  if ((threadIdx.x & 63) == 0){ A[idx >> 6] = wb; S[idx >> 6] = sb; }
}

// ---------------- hysteresis fixpoint: register-cached own column, padded LDS ----------------
__device__ __forceinline__ u64 ks_flood(u64 g, u64 P){
  u64 p1 = P, g1 = g;
  g1 |= p1 & (g1 << 1);  p1 &= (p1 << 1);
  g1 |= p1 & (g1 << 2);  p1 &= (p1 << 2);
  g1 |= p1 & (g1 << 4);  p1 &= (p1 << 4);
  g1 |= p1 & (g1 << 8);  p1 &= (p1 << 8);
  g1 |= p1 & (g1 << 16); p1 &= (p1 << 16);
  g1 |= p1 & (g1 << 32);
  u64 p2 = P, g2 = g;
  g2 |= p2 & (g2 >> 1);  p2 &= (p2 >> 1);
  g2 |= p2 & (g2 >> 2);  p2 &= (p2 >> 2);
  g2 |= p2 & (g2 >> 4);  p2 &= (p2 >> 4);
  g2 |= p2 & (g2 >> 8);  p2 &= (p2 >> 8);
  g2 |= p2 & (g2 >> 16); p2 &= (p2 >> 16);
  g2 |= p2 & (g2 >> 32);
  return g1 | g2;
}

#define HROW(m, l, r_) ((m) | ((m)<<1) | ((m)>>1) | ((l)>>63) | ((r_)<<63))

// races on monotone OR-propagation are safe: bits only get set; loop exits only
// after a full barrier round with zero changes anywhere -> exact fixpoint
#define UPD(i) do{ \
    u64 P = Pr[i]; \
    if (P){ \
      u64 Sv = Sr[i]; \
      int r = r0 + (i); \
      u64 mu = ((i) > 0) ? Sr[(i)-1] : (r > 0   ? sS[(r-1)*9+w] : 0ull); \
      u64 md = ((i) < 7) ? Sr[(i)+1] : (r < 511 ? sS[(r+1)*9+w] : 0ull); \
      u64 lu = (left  && r > 0)   ? sS[(r-1)*9+w-1] : 0ull; \
      u64 ru = (right && r > 0)   ? sS[(r-1)*9+w+1] : 0ull; \
      u64 lm = left  ? sS[r*9+w-1] : 0ull; \
      u64 rm = right ? sS[r*9+w+1] : 0ull; \
      u64 ldn= (left  && r < 511) ? sS[(r+1)*9+w-1] : 0ull; \
      u64 rdn= (right && r < 511) ? sS[(r+1)*9+w+1] : 0ull; \
      u64 nb = HROW(mu,lu,ru) | HROW(Sv,lm,rm) | HROW(md,ldn,rdn); \
      u64 g = Sv | (P & nb); \
      if (g != Sv){ \
        u64 ns = ks_flood(g, P); \
        Sr[i] = ns; sS[r*9+w] = ns; changed = true; \
      } \
    } \
  } while(0)

__global__ void __launch_bounds__(512) k_hyst(const u64* __restrict__ A, u64* __restrict__ S)
{
  __shared__ u64 sS[512*9];   // stride 9 u64: breaks 8-way bank aliasing to 4-way
  int img = blockIdx.x;
  const u64* gA = A + img * 4096;
  u64*       gS = S + img * 4096;
  int tid = threadIdx.x;
  for (int i = tid; i < 4096; i += 512)
    sS[(i>>3)*9 + (i&7)] = gS[i];
  __syncthreads();
  int  w     = tid & 7;
  int  r0    = (tid >> 3) << 3;
  bool left  = (w > 0), right = (w < 7);
  u64 Sr[8], Pr[8];
  #pragma unroll
  for (int i = 0; i < 8; i++){
    Sr[i] = sS[(r0+i)*9 + w];
    Pr[i] = gA[(r0+i)*8 + w] | Sr[i];
  }
  for (;;){
    bool changed = false;
    #pragma unroll 1
    for (int rep = 0; rep < 2; rep++){
      #pragma unroll
      for (int i = 0; i < 8; i++) UPD(i);
      #pragma unroll
      for (int i = 7; i >= 0; i--) UPD(i);
    }
    if (!__syncthreads_or(changed ? 1 : 0)) break;
  }
  #pragma unroll
  for (int i = 0; i < 8; i++) gS[(r0+i)*8 + w] = Sr[i];
}

// ---------------- 11-tap horizontal Gaussian directly from edge bitmask ----------------
__global__ void k_b11h(const u64* __restrict__ S, float* __restrict__ out)
{
#pragma clang fp contract(off)
  int idx = blockIdx.x * 256 + threadIdx.x;
  int img = idx >> 18;
  int p   = idx & (HW - 1);
  int y = p >> 9, xc = p & 511;
  float g[11]; float s = 0.0f;
  for (int i = 0; i < 11; i++){ float t = (float)i - 5.0f; g[i] = expf(-(t*t)/4.5f); s += g[i]; }
  for (int i = 0; i < 11; i++) g[i] /= s;
  const u64* row = S + img*4096 + y*8;
  float acc = 0.0f;
  for (int k = 0; k < 11; k++){
    int xx = refl(xc + k - 5, WW);
    float bv = (float)((row[xx >> 6] >> (xx & 63)) & 1ull);
    acc += g[k] * bv;
  }
  out[idx] = acc;
}

// vertical pass; per-block (min,max) partials -> part[]
__global__ void k_b11v(const float* __restrict__ in, float* __restrict__ out, float2* __restrict__ part)
{
#pragma clang fp contract(off)
  int idx = blockIdx.x * 256 + threadIdx.x;
  int img = idx >> 18;
  int p   = idx & (HW - 1);
  int y = p >> 9, xc = p & 511;
  float g[11]; float s = 0.0f;
  for (int i = 0; i < 11; i++){ float t = (float)i - 5.0f; g[i] = expf(-(t*t)/4.5f); s += g[i]; }
  for (int i = 0; i < 11; i++) g[i] /= s;
  const float* ib = in + (size_t)img*HW;
  float acc = 0.0f;
  for (int k = 0; k < 11; k++){ int yy = refl(y + k - 5, HH); acc += g[k] * ib[yy*WW + xc]; }
  out[idx] = acc;
  float mn = acc, mx = acc;
  for (int off = 32; off >= 1; off >>= 1){
    mn = fminf(mn, __shfl_down(mn, off));
    mx = fmaxf(mx, __shfl_down(mx, off));
  }
  __shared__ float smn[4], smx[4];
  int wv = threadIdx.x >> 6, ln = threadIdx.x & 63;
  if (ln == 0){ smn[wv] = mn; smx[wv] = mx; }
  __syncthreads();
  if (threadIdx.x == 0){
    float a = fminf(fminf(smn[0], smn[1]), fminf(smn[2], smn[3]));
    float b = fmaxf(fmaxf(smx[0], smx[1]), fmaxf(smx[2], smx[3]));
    part[blockIdx.x] = make_float2(a, b);
  }
}

// reduce 1024 per-block partials per image -> stats
__global__ void k_edred(const float2* __restrict__ part, uint32_t* __restrict__ stats){
  int img = blockIdx.x;
  const float2* pp = part + img * 1024;
  float mn =  3.4e38f, mx = -3.4e38f;
  for (int i = threadIdx.x; i < 1024; i += 256){
    float2 v = pp[i];
    mn = fminf(mn, v.x); mx = fmaxf(mx, v.y);
  }
  for (int off = 32; off >= 1; off >>= 1){
    mn = fminf(mn, __shfl_down(mn, off));
    mx = fmaxf(mx, __shfl_down(mx, off));
  }
  __shared__ float smn[4], smx[4];
  int wv = threadIdx.x >> 6, ln = threadIdx.x & 63;
  if (ln == 0){ smn[wv] = mn; smx[wv] = mx; }
  __syncthreads();
  if (threadIdx.x == 0){
    float a = fminf(fminf(smn[0], smn[1]), fminf(smn[2], smn[3]));
    float b = fmaxf(fmaxf(smx[0], smx[1]), fmaxf(smx[2], smx[3]));
    stats[img*4+0] = __float_as_uint(a);
    stats[img*4+1] = __float_as_uint(b);
  }
}

// ---------------- fuse: normalize both maps, sigmoid ----------------
__global__ void k_final(const float* __restrict__ ed, const uint16_t* __restrict__ comb,
                        const uint32_t* __restrict__ hist, const uint32_t* __restrict__ stats,
                        const float* __restrict__ alpha, const float* __restrict__ beta,
                        float* __restrict__ out)
{
#pragma clang fp contract(off)
  int idx = blockIdx.x * 256 + threadIdx.x;
  int img = idx >> 18;
  float a = alpha[0], b = beta[0];
  float mne = __uint_as_float(stats[img*4+0]);
  float mxe = __uint_as_float(stats[img*4+1]);
  float mns = __uint_as_float(stats[img*4+2]);
  float mxs = __uint_as_float(stats[img*4+3]);
  float e  = ed[idx];
  float sp = -logf((float)hist[img*NBINS + comb[idx]] / 262144.0f + 1e-9f);
  float en = (e  - mne) / (mxe - mne + 1e-9f);
  float sn = (sp - mns) / (mxs - mns + 1e-9f);
  float f  = a*en + b*sn;
  out[idx] = 1.0f / (1.0f + expf(-f));
}

extern "C" void kernel_launch(void* const* d_in, const int* in_sizes, int n_in,
                              void* d_out, int out_size, void* d_ws, size_t ws_size,
                              hipStream_t stream)
{
  const float* x     = (const float*)d_in[0];
  const float* mean  = (const float*)d_in[1];
  const float* stdv  = (const float*)d_in[2];
  const float* alpha = (const float*)d_in[3];
  const float* beta  = (const float*)d_in[4];
  float* out = (float*)d_out;

  char* ws = (char*)d_ws;
  float*    buf0  = (float*)ws;                                   // 16 MB (gray -> mag -> tmp11)
  uint16_t* comb  = (uint16_t*)(ws + (16u << 20));                // 8 MB
  uint8_t*  dir   = (uint8_t*)(ws + (24u << 20));                 // 4 MB (dead after k_nms)
  float2*   part  = (float2*)(ws + (24u << 20));                  // aliases dir
  uint32_t* hist  = (uint32_t*)(ws + (28u << 20));                // 256 KB
  u64*      Ab    = (u64*)(ws + (28u << 20) + (1u << 18));               // 512 KB
  u64*      Sb    = (u64*)(ws + (28u << 20) + (1u << 18) + (1u << 19));  // 512 KB
  uint32_t* stats = (uint32_t*)(ws + (28u << 20) + (1u << 18) + (2u << 19));  // 256 B

  hipMemsetAsync(hist, 0, NB * NBINS * sizeof(uint32_t), stream);
  hipLaunchKernelGGL(k_prep, dim3(1024), dim3(256), 0, stream, x, mean, stdv, buf0, comb, hist);
  hipLaunchKernelGGL(k_spb,  dim3(NB), dim3(256), 0, stream, hist, stats);
  hipLaunchKernelGGL(k_blur5, dim3(16384), dim3(256), 0, stream, buf0, out);         // blurred -> d_out
  hipLaunchKernelGGL(k_sobel, dim3(16384), dim3(256), 0, stream, out, buf0, dir);    // mag -> buf0
  hipLaunchKernelGGL(k_nms,   dim3(16384), dim3(256), 0, stream, buf0, dir, Ab, Sb);
  hipLaunchKernelGGL(k_hyst,  dim3(NB), dim3(512), 0, stream, Ab, Sb);
  hipLaunchKernelGGL(k_b11h,  dim3(16384), dim3(256), 0, stream, Sb, buf0);          // tmp -> buf0
  hipLaunchKernelGGL(k_b11v,  dim3(16384), dim3(256), 0, stream, buf0, out, part);   // density -> d_out
  hipLaunchKernelGGL(k_edred, dim3(NB), dim3(256), 0, stream, part, stats);
  hipLaunchKernelGGL(k_final, dim3(16384), dim3(256), 0, stream, out, comb, hist, stats, alpha, beta, out);
}

// Round 5
// 177.504 us; speedup vs baseline: 2.2204x; 1.0509x over previous
//
#include <hip/hip_runtime.h>
#include <stdint.h>

#define NB 16
#define HH 512
#define WW 512
#define HW (HH*WW)          // 262144
#define NBINS 4096

typedef unsigned long long u64;

__device__ __forceinline__ float clip01(float v){ return fminf(fmaxf(v, 0.0f), 1.0f); }
__device__ __forceinline__ int refl(int i, int n){ if (i < 0) i = -i; if (i >= n) i = 2*n - 2 - i; return i; }
__device__ __forceinline__ int clampi(int i, int lo, int hi){ return i < lo ? lo : (i > hi ? hi : i); }

// ---------------- zero the histogram (replaces pathological rocclr fill) ----------------
__global__ void k_zero(uint4* __restrict__ hist4){
  int idx = blockIdx.x * 256 + threadIdx.x;    // 64 blocks x 256 = 16384 uint4 = 256 KB
  hist4[idx] = make_uint4(0u, 0u, 0u, 0u);
}

// ---------------- denorm + gray + quantized bins + histogram (vectorized) ----------------
__global__ void k_prep(const float* __restrict__ x, const float* __restrict__ mean,
                       const float* __restrict__ stdv, float* __restrict__ gray,
                       uint16_t* __restrict__ comb, uint32_t* __restrict__ hist)
{
#pragma clang fp contract(off)
  __shared__ uint32_t h[NBINS];
  for (int i = threadIdx.x; i < NBINS; i += 256) h[i] = 0u;
  __syncthreads();
  int img  = blockIdx.x >> 6;
  int base = (blockIdx.x & 63) * 4096;
  float m0 = mean[0], m1 = mean[1], m2 = mean[2];
  float s0 = stdv[0], s1 = stdv[1], s2 = stdv[2];
  const float* xb = x + (size_t)img * 3 * HW;
  float*     gb   = gray + (size_t)img*HW;
  uint16_t*  cb   = comb + (size_t)img*HW;
  #pragma unroll
  for (int it = 0; it < 4; it++){
    int f4 = it*256 + threadIdx.x;
    int p  = base + f4*4;
    float4 r = *(const float4*)(xb + p);
    float4 g = *(const float4*)(xb + HW + p);
    float4 b = *(const float4*)(xb + 2*HW + p);
    float xr[4] = {r.x, r.y, r.z, r.w};
    float xg[4] = {g.x, g.y, g.z, g.w};
    float xbl[4] = {b.x, b.y, b.z, b.w};
    float gy[4]; uint16_t cc[4];
    #pragma unroll
    for (int j = 0; j < 4; j++){
      float cr = clip01(xr[j]*s0 + m0);
      float cg = clip01(xg[j]*s1 + m1);
      float cbv= clip01(xbl[j]*s2 + m2);
      gy[j] = 0.299f*cr + 0.587f*cg + 0.114f*cbv;
      int c = ((int)rintf(cr*15.0f))*256 + ((int)rintf(cg*15.0f))*16 + (int)rintf(cbv*15.0f);
      cc[j] = (uint16_t)c;
      atomicAdd(&h[c], 1u);
    }
    *(float4*)(gb + p) = make_float4(gy[0], gy[1], gy[2], gy[3]);
    ushort4 cv; cv.x = cc[0]; cv.y = cc[1]; cv.z = cc[2]; cv.w = cc[3];
    *(ushort4*)(cb + p) = cv;
  }
  __syncthreads();
  uint32_t* gh = hist + img * NBINS;
  for (int i = threadIdx.x; i < NBINS; i += 256){ uint32_t v = h[i]; if (v) atomicAdd(&gh[i], v); }
}

// ---------------- sparsity min/max from histogram ----------------
__global__ void k_spb(const uint32_t* __restrict__ hist, uint32_t* __restrict__ stats){
  int img = blockIdx.x;
  uint32_t mx = 0u, mn = 0xFFFFFFFFu;
  for (int i = threadIdx.x; i < NBINS; i += 256){
    uint32_t c = hist[img*NBINS + i];
    if (c > mx) mx = c;
    if (c > 0u && c < mn) mn = c;
  }
  __shared__ uint32_t rmx[256], rmn[256];
  rmx[threadIdx.x] = mx; rmn[threadIdx.x] = mn;
  __syncthreads();
  for (int s = 128; s > 0; s >>= 1){
    if (threadIdx.x < (unsigned)s){
      rmx[threadIdx.x] = max(rmx[threadIdx.x], rmx[threadIdx.x + s]);
      rmn[threadIdx.x] = min(rmn[threadIdx.x], rmn[threadIdx.x + s]);
    }
    __syncthreads();
  }
  if (threadIdx.x == 0){
    float sp_min = -logf((float)rmx[0] / 262144.0f + 1e-9f);
    float sp_max = -logf((float)rmn[0] / 262144.0f + 1e-9f);
    stats[img*4+2] = __float_as_uint(sp_min);
    stats[img*4+3] = __float_as_uint(sp_max);
  }
}

// ---------------- 5x5 Gaussian blur (sigma=1), reflect pad ----------------
__global__ void k_blur5(const float* __restrict__ gray, float* __restrict__ out)
{
#pragma clang fp contract(off)
  int idx = blockIdx.x * 256 + threadIdx.x;
  int img = idx >> 18;
  int p   = idx & (HW - 1);
  int y = p >> 9, xc = p & 511;
  float g[5]; float s = 0.0f;
  for (int i = 0; i < 5; i++){ float t = (float)i - 2.0f; g[i] = expf(-(t*t)/2.0f); s += g[i]; }
  for (int i = 0; i < 5; i++) g[i] /= s;
  const float* gb = gray + (size_t)img*HW;
  float acc = 0.0f;
  for (int ky = 0; ky < 5; ky++){
    int yy = refl(y + ky - 2, HH);
    const float* row = gb + yy*WW;
    for (int kx = 0; kx < 5; kx++){
      int xx = refl(xc + kx - 2, WW);
      acc += (g[ky]*g[kx]) * row[xx];
    }
  }
  out[idx] = acc;
}

// ---------------- Sobel (edge/replicate pad) -> mag + direction ----------------
__global__ void k_sobel(const float* __restrict__ blur, float* __restrict__ mag, uint8_t* __restrict__ dir)
{
#pragma clang fp contract(off)
  int idx = blockIdx.x * 256 + threadIdx.x;
  int img = idx >> 18;
  int p   = idx & (HW - 1);
  int y = p >> 9, xc = p & 511;
  const float* b = blur + (size_t)img*HW;
  float v[3][3];
  for (int dy = 0; dy < 3; dy++){
    int yy = clampi(y + dy - 1, 0, HH-1);
    for (int dx = 0; dx < 3; dx++){
      int xx = clampi(xc + dx - 1, 0, WW-1);
      v[dy][dx] = b[yy*WW + xx];
    }
  }
  float gx = (v[0][2] - v[0][0]) + 2.0f*(v[1][2] - v[1][0]) + (v[2][2] - v[2][0]);
  float gy = (v[2][0] + 2.0f*v[2][1] + v[2][2]) - (v[0][0] + 2.0f*v[0][1] + v[0][2]);
  float m = sqrtf(gx*gx + gy*gy + 1e-6f);
  float ang = atan2f(gy, gx) * 57.29577951308232f;
  int ai = (int)rintf(ang / 45.0f);
  mag[idx] = m;
  dir[idx] = (uint8_t)(ai & 7);
}

// ---------------- NMS + double threshold -> bitmasks (weak, strong) ----------------
__global__ void k_nms(const float* __restrict__ mag, const uint8_t* __restrict__ dir,
                      u64* __restrict__ A, u64* __restrict__ S)
{
  int idx = blockIdx.x * 256 + threadIdx.x;
  int img = idx >> 18;
  int p   = idx & (HW - 1);
  int y = p >> 9, xc = p & 511;
  const float* mb = mag + (size_t)img*HW;
  float m = mb[p];
  int d  = dir[idx];
  int d2 = (d + 4) & 7;
  const int OY[8] = {0,1,1,1,0,-1,-1,-1};
  const int OX[8] = {1,1,0,-1,-1,-1,0,1};
  float mp = 0.0f, mn = 0.0f;
  { int yy = y + OY[d],  xx = xc + OX[d];  if (yy>=0 && yy<HH && xx>=0 && xx<WW) mp = mb[yy*WW+xx]; }
  { int yy = y + OY[d2], xx = xc + OX[d2]; if (yy>=0 && yy<HH && xx>=0 && xx<WW) mn = mb[yy*WW+xx]; }
  bool keep = ((m - mp) > 0.0f) && ((m - mn) > 0.0f);
  float mf = keep ? m : 0.0f;
  bool strong = mf > 0.2f;
  bool weak   = (mf > 0.1f) && !(mf > 0.2f);
  u64 wb = __ballot(weak);
  u64 sb = __ballot(strong);
  if ((threadIdx.x & 63) == 0){ A[idx >> 6] = wb; S[idx >> 6] = sb; }
}

// ---------------- hysteresis fixpoint v3 ----------------
// exact fixpoint: monotone OR-propagation (bits only set); loop exits only after
// a full barrier round with zero changes. Staleness from rolling regs / skip
// flags only delays propagation, never loses it (writer always flags change).
__device__ __forceinline__ u64 ks_flood(u64 g, u64 P){
  u64 p1 = P, g1 = g;
  g1 |= p1 & (g1 << 1);  p1 &= (p1 << 1);
  g1 |= p1 & (g1 << 2);  p1 &= (p1 << 2);
  g1 |= p1 & (g1 << 4);  p1 &= (p1 << 4);
  g1 |= p1 & (g1 << 8);  p1 &= (p1 << 8);
  g1 |= p1 & (g1 << 16); p1 &= (p1 << 16);
  g1 |= p1 & (g1 << 32);
  u64 p2 = P, g2 = g;
  g2 |= p2 & (g2 >> 1);  p2 &= (p2 >> 1);
  g2 |= p2 & (g2 >> 2);  p2 &= (p2 >> 2);
  g2 |= p2 & (g2 >> 4);  p2 &= (p2 >> 4);
  g2 |= p2 & (g2 >> 8);  p2 &= (p2 >> 8);
  g2 |= p2 & (g2 >> 16); p2 &= (p2 >> 16);
  g2 |= p2 & (g2 >> 32);
  return g1 | g2;
}

#define HROW(m, l, r_) ((m) | ((m)<<1) | ((m)>>1) | ((l)>>63) | ((r_)<<63))

#define UPD_BODY(i, MU_, MD_, LU_, LM_, RU_, RM_, LD_, RD_) do{ \
    u64 pend = Pr[i] & ~Sr[i]; \
    if (pend){ \
      u64 Sv = Sr[i]; \
      u64 nb = HROW((MU_),(LU_),(RU_)) | HROW(Sv,(LM_),(RM_)) | HROW((MD_),(LD_),(RD_)); \
      u64 gg = Sv | (Pr[i] & nb); \
      if (gg != Sv){ \
        u64 ns = ks_flood(gg, Pr[i]); \
        Sr[i] = ns; sS[(r0+(i))*9+w] = ns; changed = true; \
      } \
    } \
  } while(0)

__global__ void __launch_bounds__(512) k_hyst(const u64* __restrict__ A, u64* __restrict__ S)
{
  __shared__ u64 sS[512*9];                      // stride-9 padding
  __shared__ __align__(8) uint8_t gch[2][64][8]; // frontier flags, double-buffered
  int img = blockIdx.x;
  const u64* gA = A + img * 4096;
  u64*       gS = S + img * 4096;
  int tid = threadIdx.x;
  for (int i = tid; i < 4096; i += 512)
    sS[(i>>3)*9 + (i&7)] = gS[i];
  int  w   = tid & 7;
  int  g   = tid >> 3;
  int  r0  = g << 3;
  bool left  = (w > 0), right = (w < 7);
  gch[0][g][w] = 1;    // round 1: everything active
  gch[1][g][w] = 0;
  __syncthreads();
  u64 Sr[8], Pr[8];
  #pragma unroll
  for (int i = 0; i < 8; i++){
    Sr[i] = sS[(r0+i)*9 + w];
    Pr[i] = gA[(r0+i)*8 + w] | Sr[i];
  }
  u64 nbmask = 0xFFull << (w*8);
  if (left)  nbmask |= 0xFFull << ((w-1)*8);
  if (right) nbmask |= 0xFFull << ((w+1)*8);
  int pb = 0, cbuf = 1;
  for (;;){
    u64 f  =              *(const u64*)gch[pb][g];
    if (g > 0)  f |= *(const u64*)gch[pb][g-1];
    if (g < 63) f |= *(const u64*)gch[pb][g+1];
    bool changed = false;
    if (f & nbmask){
      #pragma unroll 1
      for (int rep = 0; rep < 2; rep++){
        // ---- down sweep: rolling neighbor-column registers ----
        {
          u64 L0=0, L1=0, R0=0, R1=0, MU=0;
          if (r0 > 0){
            MU = sS[(r0-1)*9+w];
            if (left)  L0 = sS[(r0-1)*9+w-1];
            if (right) R0 = sS[(r0-1)*9+w+1];
          }
          if (left)  L1 = sS[r0*9+w-1];
          if (right) R1 = sS[r0*9+w+1];
          #pragma unroll
          for (int i = 0; i < 8; i++){
            int r = r0 + i;
            bool below = (r < 511);
            u64 L2=0, R2=0;
            if (below){
              if (left)  L2 = sS[(r+1)*9+w-1];
              if (right) R2 = sS[(r+1)*9+w+1];
            }
            u64 md = (i < 7) ? Sr[i+1] : (below ? sS[(r+1)*9+w] : 0ull);
            u64 mu = (i > 0) ? Sr[i-1] : MU;
            UPD_BODY(i, mu, md, L0, L1, R0, R1, L2, R2);
            L0 = L1; L1 = L2; R0 = R1; R1 = R2;
          }
        }
        // ---- up sweep ----
        {
          int rb = r0 + 7;
          u64 LD=0, RD=0, LM=0, RM=0, MD=0;
          if (rb < 511){
            MD = sS[(rb+1)*9+w];
            if (left)  LD = sS[(rb+1)*9+w-1];
            if (right) RD = sS[(rb+1)*9+w+1];
          }
          if (left)  LM = sS[rb*9+w-1];
          if (right) RM = sS[rb*9+w+1];
          #pragma unroll
          for (int i = 7; i >= 0; i--){
            int r = r0 + i;
            bool above = (r > 0);
            u64 LU=0, RU=0;
            if (above){
              if (left)  LU = sS[(r-1)*9+w-1];
              if (right) RU = sS[(r-1)*9+w+1];
            }
            u64 mu = (i > 0) ? Sr[i-1] : (above ? sS[(r-1)*9+w] : 0ull);
            u64 md = (i < 7) ? Sr[i+1] : MD;
            UPD_BODY(i, mu, md, LU, LM, RU, RM, LD, RD);
            LD = LM; LM = LU; RD = RM; RM = RU;
          }
        }
      }
      if (changed) gch[cbuf][g][w] = 1;
    }
    __syncthreads();                 // cur-flag writes + prev-flag reads complete
    gch[pb][g][w] = 0;               // clear prev (becomes next round's cur)
    if (!__syncthreads_or(changed ? 1 : 0)) break;
    int t = pb; pb = cbuf; cbuf = t;
  }
  #pragma unroll
  for (int i = 0; i < 8; i++) gS[(r0+i)*8 + w] = Sr[i];
}

// ---------------- 11-tap horizontal Gaussian directly from edge bitmask ----------------
__global__ void k_b11h(const u64* __restrict__ S, float* __restrict__ out)
{
#pragma clang fp contract(off)
  int idx = blockIdx.x * 256 + threadIdx.x;
  int img = idx >> 18;
  int p   = idx & (HW - 1);
  int y = p >> 9, xc = p & 511;
  float g[11]; float s = 0.0f;
  for (int i = 0; i < 11; i++){ float t = (float)i - 5.0f; g[i] = expf(-(t*t)/4.5f); s += g[i]; }
  for (int i = 0; i < 11; i++) g[i] /= s;
  const u64* row = S + img*4096 + y*8;
  float acc = 0.0f;
  for (int k = 0; k < 11; k++){
    int xx = refl(xc + k - 5, WW);
    float bv = (float)((row[xx >> 6] >> (xx & 63)) & 1ull);
    acc += g[k] * bv;
  }
  out[idx] = acc;
}

// vertical pass; per-block (min,max) partials -> part[]
__global__ void k_b11v(const float* __restrict__ in, float* __restrict__ out, float2* __restrict__ part)
{
#pragma clang fp contract(off)
  int idx = blockIdx.x * 256 + threadIdx.x;
  int img = idx >> 18;
  int p   = idx & (HW - 1);
  int y = p >> 9, xc = p & 511;
  float g[11]; float s = 0.0f;
  for (int i = 0; i < 11; i++){ float t = (float)i - 5.0f; g[i] = expf(-(t*t)/4.5f); s += g[i]; }
  for (int i = 0; i < 11; i++) g[i] /= s;
  const float* ib = in + (size_t)img*HW;
  float acc = 0.0f;
  for (int k = 0; k < 11; k++){ int yy = refl(y + k - 5, HH); acc += g[k] * ib[yy*WW + xc]; }
  out[idx] = acc;
  float mn = acc, mx = acc;
  for (int off = 32; off >= 1; off >>= 1){
    mn = fminf(mn, __shfl_down(mn, off));
    mx = fmaxf(mx, __shfl_down(mx, off));
  }
  __shared__ float smn[4], smx[4];
  int wv = threadIdx.x >> 6, ln = threadIdx.x & 63;
  if (ln == 0){ smn[wv] = mn; smx[wv] = mx; }
  __syncthreads();
  if (threadIdx.x == 0){
    float a = fminf(fminf(smn[0], smn[1]), fminf(smn[2], smn[3]));
    float b = fmaxf(fmaxf(smx[0], smx[1]), fmaxf(smx[2], smx[3]));
    part[blockIdx.x] = make_float2(a, b);
  }
}

// reduce 1024 per-block partials per image -> stats
__global__ void k_edred(const float2* __restrict__ part, uint32_t* __restrict__ stats){
  int img = blockIdx.x;
  const float2* pp = part + img * 1024;
  float mn =  3.4e38f, mx = -3.4e38f;
  for (int i = threadIdx.x; i < 1024; i += 256){
    float2 v = pp[i];
    mn = fminf(mn, v.x); mx = fmaxf(mx, v.y);
  }
  for (int off = 32; off >= 1; off >>= 1){
    mn = fminf(mn, __shfl_down(mn, off));
    mx = fmaxf(mx, __shfl_down(mx, off));
  }
  __shared__ float smn[4], smx[4];
  int wv = threadIdx.x >> 6, ln = threadIdx.x & 63;
  if (ln == 0){ smn[wv] = mn; smx[wv] = mx; }
  __syncthreads();
  if (threadIdx.x == 0){
    float a = fminf(fminf(smn[0], smn[1]), fminf(smn[2], smn[3]));
    float b = fmaxf(fmaxf(smx[0], smx[1]), fmaxf(smx[2], smx[3]));
    stats[img*4+0] = __float_as_uint(a);
    stats[img*4+1] = __float_as_uint(b);
  }
}

// ---------------- fuse: normalize both maps, sigmoid ----------------
__global__ void k_final(const float* __restrict__ ed, const uint16_t* __restrict__ comb,
                        const uint32_t* __restrict__ hist, const uint32_t* __restrict__ stats,
                        const float* __restrict__ alpha, const float* __restrict__ beta,
                        float* __restrict__ out)
{
#pragma clang fp contract(off)
  int idx = blockIdx.x * 256 + threadIdx.x;
  int img = idx >> 18;
  float a = alpha[0], b = beta[0];
  float mne = __uint_as_float(stats[img*4+0]);
  float mxe = __uint_as_float(stats[img*4+1]);
  float mns = __uint_as_float(stats[img*4+2]);
  float mxs = __uint_as_float(stats[img*4+3]);
  float e  = ed[idx];
  float sp = -logf((float)hist[img*NBINS + comb[idx]] / 262144.0f + 1e-9f);
  float en = (e  - mne) / (mxe - mne + 1e-9f);
  float sn = (sp - mns) / (mxs - mns + 1e-9f);
  float f  = a*en + b*sn;
  out[idx] = 1.0f / (1.0f + expf(-f));
}

extern "C" void kernel_launch(void* const* d_in, const int* in_sizes, int n_in,
                              void* d_out, int out_size, void* d_ws, size_t ws_size,
                              hipStream_t stream)
{
  const float* x     = (const float*)d_in[0];
  const float* mean  = (const float*)d_in[1];
  const float* stdv  = (const float*)d_in[2];
  const float* alpha = (const float*)d_in[3];
  const float* beta  = (const float*)d_in[4];
  float* out = (float*)d_out;

  char* ws = (char*)d_ws;
  float*    buf0  = (float*)ws;                                   // 16 MB (gray -> mag -> tmp11)
  uint16_t* comb  = (uint16_t*)(ws + (16u << 20));                // 8 MB
  uint8_t*  dir   = (uint8_t*)(ws + (24u << 20));                 // 4 MB (dead after k_nms)
  float2*   part  = (float2*)(ws + (24u << 20));                  // aliases dir
  uint32_t* hist  = (uint32_t*)(ws + (28u << 20));                // 256 KB
  u64*      Ab    = (u64*)(ws + (28u << 20) + (1u << 18));               // 512 KB
  u64*      Sb    = (u64*)(ws + (28u << 20) + (1u << 18) + (1u << 19));  // 512 KB
  uint32_t* stats = (uint32_t*)(ws + (28u << 20) + (1u << 18) + (2u << 19));  // 256 B

  hipLaunchKernelGGL(k_zero, dim3(64), dim3(256), 0, stream, (uint4*)hist);
  hipLaunchKernelGGL(k_prep, dim3(1024), dim3(256), 0, stream, x, mean, stdv, buf0, comb, hist);
  hipLaunchKernelGGL(k_spb,  dim3(NB), dim3(256), 0, stream, hist, stats);
  hipLaunchKernelGGL(k_blur5, dim3(16384), dim3(256), 0, stream, buf0, out);         // blurred -> d_out
  hipLaunchKernelGGL(k_sobel, dim3(16384), dim3(256), 0, stream, out, buf0, dir);    // mag -> buf0
  hipLaunchKernelGGL(k_nms,   dim3(16384), dim3(256), 0, stream, buf0, dir, Ab, Sb);
  hipLaunchKernelGGL(k_hyst,  dim3(NB), dim3(512), 0, stream, Ab, Sb);
  hipLaunchKernelGGL(k_b11h,  dim3(16384), dim3(256), 0, stream, Sb, buf0);          // tmp -> buf0
  hipLaunchKernelGGL(k_b11v,  dim3(16384), dim3(256), 0, stream, buf0, out, part);   // density -> d_out
  hipLaunchKernelGGL(k_edred, dim3(NB), dim3(256), 0, stream, part, stats);
  hipLaunchKernelGGL(k_final, dim3(16384), dim3(256), 0, stream, out, comb, hist, stats, alpha, beta, out);
}

// Round 6
// 160.072 us; speedup vs baseline: 2.4622x; 1.1089x over previous
//
#include <hip/hip_runtime.h>
#include <stdint.h>

#define NB 16
#define HH 512
#define WW 512
#define HW (HH*WW)          // 262144
#define NBINS 4096

typedef unsigned long long u64;

__device__ __forceinline__ float clip01(float v){ return fminf(fmaxf(v, 0.0f), 1.0f); }
__device__ __forceinline__ int refl(int i, int n){ if (i < 0) i = -i; if (i >= n) i = 2*n - 2 - i; return i; }
__device__ __forceinline__ int clampi(int i, int lo, int hi){ return i < lo ? lo : (i > hi ? hi : i); }

// ---------------- zero the histogram ----------------
__global__ void k_zero(uint4* __restrict__ hist4){
  int idx = blockIdx.x * 256 + threadIdx.x;    // 64 x 256 = 16384 uint4 = 256 KB
  hist4[idx] = make_uint4(0u, 0u, 0u, 0u);
}

// ---------------- denorm + gray + quantized bins + histogram ----------------
__global__ void k_prep(const float* __restrict__ x, const float* __restrict__ mean,
                       const float* __restrict__ stdv, float* __restrict__ gray,
                       uint16_t* __restrict__ comb, uint32_t* __restrict__ hist)
{
#pragma clang fp contract(off)
  __shared__ uint32_t h[NBINS];
  for (int i = threadIdx.x; i < NBINS; i += 256) h[i] = 0u;
  __syncthreads();
  int img  = blockIdx.x >> 6;
  int base = (blockIdx.x & 63) * 4096;
  float m0 = mean[0], m1 = mean[1], m2 = mean[2];
  float s0 = stdv[0], s1 = stdv[1], s2 = stdv[2];
  const float* xb = x + (size_t)img * 3 * HW;
  float*     gb   = gray + (size_t)img*HW;
  uint16_t*  cb   = comb + (size_t)img*HW;
  #pragma unroll
  for (int it = 0; it < 4; it++){
    int f4 = it*256 + threadIdx.x;
    int p  = base + f4*4;
    float4 r = *(const float4*)(xb + p);
    float4 g = *(const float4*)(xb + HW + p);
    float4 b = *(const float4*)(xb + 2*HW + p);
    float xr[4] = {r.x, r.y, r.z, r.w};
    float xg[4] = {g.x, g.y, g.z, g.w};
    float xbl[4] = {b.x, b.y, b.z, b.w};
    float gy[4]; uint16_t cc[4];
    #pragma unroll
    for (int j = 0; j < 4; j++){
      float cr = clip01(xr[j]*s0 + m0);
      float cg = clip01(xg[j]*s1 + m1);
      float cbv= clip01(xbl[j]*s2 + m2);
      gy[j] = 0.299f*cr + 0.587f*cg + 0.114f*cbv;
      int c = ((int)rintf(cr*15.0f))*256 + ((int)rintf(cg*15.0f))*16 + (int)rintf(cbv*15.0f);
      cc[j] = (uint16_t)c;
      atomicAdd(&h[c], 1u);
    }
    *(float4*)(gb + p) = make_float4(gy[0], gy[1], gy[2], gy[3]);
    ushort4 cv; cv.x = cc[0]; cv.y = cc[1]; cv.z = cc[2]; cv.w = cc[3];
    *(ushort4*)(cb + p) = cv;
  }
  __syncthreads();
  uint32_t* gh = hist + img * NBINS;
  for (int i = threadIdx.x; i < NBINS; i += 256){ uint32_t v = h[i]; if (v) atomicAdd(&gh[i], v); }
}

// ---------------- sparsity min/max from histogram ----------------
__global__ void k_spb(const uint32_t* __restrict__ hist, uint32_t* __restrict__ stats){
  int img = blockIdx.x;
  uint32_t mx = 0u, mn = 0xFFFFFFFFu;
  for (int i = threadIdx.x; i < NBINS; i += 256){
    uint32_t c = hist[img*NBINS + i];
    if (c > mx) mx = c;
    if (c > 0u && c < mn) mn = c;
  }
  __shared__ uint32_t rmx[256], rmn[256];
  rmx[threadIdx.x] = mx; rmn[threadIdx.x] = mn;
  __syncthreads();
  for (int s = 128; s > 0; s >>= 1){
    if (threadIdx.x < (unsigned)s){
      rmx[threadIdx.x] = max(rmx[threadIdx.x], rmx[threadIdx.x + s]);
      rmn[threadIdx.x] = min(rmn[threadIdx.x], rmn[threadIdx.x + s]);
    }
    __syncthreads();
  }
  if (threadIdx.x == 0){
    float sp_min = -logf((float)rmx[0] / 262144.0f + 1e-9f);
    float sp_max = -logf((float)rmn[0] / 262144.0f + 1e-9f);
    stats[img*4+2] = __float_as_uint(sp_min);
    stats[img*4+3] = __float_as_uint(sp_max);
  }
}

// ---------------- fused blur5 + sobel + NMS + threshold -> bitmasks ----------------
// 64x64 output tile per block; arithmetic copied verbatim from the unfused kernels.
__global__ void __launch_bounds__(256) k_canny(const float* __restrict__ gray,
                                               u64* __restrict__ A, u64* __restrict__ Sb)
{
#pragma clang fp contract(off)
  __shared__ float ubuf[72*73];      // gray (72x72, stride 73) then mag (66x66, stride 67)
  __shared__ float blr[68*69];       // blurred (68x68, stride 69)
  __shared__ uint8_t sdir[64*64];
  int b = blockIdx.x;
  int img = b >> 6;
  int t = b & 63;
  int y0 = (t >> 3) << 6;
  int x0 = (t & 7) << 6;
  const float* gb = gray + (size_t)img*HW;
  int tid = threadIdx.x;
  float g5[5]; { float s=0.0f; for(int i=0;i<5;i++){ float tt=(float)i-2.0f; g5[i]=expf(-(tt*tt)/2.0f); s+=g5[i]; } for(int i=0;i<5;i++) g5[i]/=s; }
  // S1: load gray tile with reflect halo 4
  for (int i = tid; i < 72*72; i += 256){
    int ly = i/72, lx = i - ly*72;
    int gy = refl(y0 - 4 + ly, HH);
    int gx = refl(x0 - 4 + lx, WW);
    ubuf[ly*73 + lx] = gb[gy*WW + gx];
  }
  __syncthreads();
  // S2: 5x5 blur (2D, same tap order as unfused) -> blurred with halo 2
  for (int i = tid; i < 68*68; i += 256){
    int ly = i/68, lx = i - ly*68;
    float acc = 0.0f;
    for (int ky = 0; ky < 5; ky++)
      for (int kx = 0; kx < 5; kx++)
        acc += (g5[ky]*g5[kx]) * ubuf[(ly+ky)*73 + (lx+kx)];
    blr[ly*69 + lx] = acc;
  }
  __syncthreads();
  // S3: sobel (clamp pad) -> mag halo 1 + dir at center; ubuf becomes mag
  for (int i = tid; i < 66*66; i += 256){
    int ly = i/66, lx = i - ly*66;
    int Y = y0 - 1 + ly, X = x0 - 1 + lx;
    float m = 0.0f;
    if (Y >= 0 && Y < HH && X >= 0 && X < WW){
      float v[3][3];
      for (int dy = 0; dy < 3; dy++){
        int Yl = clampi(Y + dy - 1, 0, HH-1) - (y0 - 2);
        for (int dx = 0; dx < 3; dx++){
          int Xl = clampi(X + dx - 1, 0, WW-1) - (x0 - 2);
          v[dy][dx] = blr[Yl*69 + Xl];
        }
      }
      float gx = (v[0][2] - v[0][0]) + 2.0f*(v[1][2] - v[1][0]) + (v[2][2] - v[2][0]);
      float gy = (v[2][0] + 2.0f*v[2][1] + v[2][2]) - (v[0][0] + 2.0f*v[0][1] + v[0][2]);
      m = sqrtf(gx*gx + gy*gy + 1e-6f);
      if (ly >= 1 && ly <= 64 && lx >= 1 && lx <= 64){
        float ang = atan2f(gy, gx) * 57.29577951308232f;
        int ai = (int)rintf(ang / 45.0f);
        sdir[(ly-1)*64 + (lx-1)] = (uint8_t)(ai & 7);
      }
    }
    ubuf[ly*67 + lx] = m;
  }
  __syncthreads();
  // S4: NMS + double threshold + ballot (tile width 64 = one mask word per row)
  const int OY[8] = {0,1,1,1,0,-1,-1,-1};
  const int OX[8] = {1,1,0,-1,-1,-1,0,1};
  int lane = tid & 63, wv = tid >> 6;
  for (int j = 0; j < 16; j++){
    int y = j*4 + wv;
    int x = lane;
    float m = ubuf[(y+1)*67 + (x+1)];
    int d  = sdir[y*64 + x];
    int d2 = (d + 4) & 7;
    float mp = 0.0f, mn = 0.0f;
    { int yy=y+OY[d],  xx=x+OX[d];  int gy=y0+yy, gx=x0+xx; if(gy>=0&&gy<HH&&gx>=0&&gx<WW) mp = ubuf[(yy+1)*67 + (xx+1)]; }
    { int yy=y+OY[d2], xx=x+OX[d2]; int gy=y0+yy, gx=x0+xx; if(gy>=0&&gy<HH&&gx>=0&&gx<WW) mn = ubuf[(yy+1)*67 + (xx+1)]; }
    bool keep = ((m - mp) > 0.0f) && ((m - mn) > 0.0f);
    float mf = keep ? m : 0.0f;
    bool strong = mf > 0.2f;
    bool weak   = (mf > 0.1f) && !strong;
    u64 wb = __ballot(weak);
    u64 sb = __ballot(strong);
    if (lane == 0){
      int gy = y0 + y;
      A [img*4096 + gy*8 + (x0>>6)] = wb;
      Sb[img*4096 + gy*8 + (x0>>6)] = sb;
    }
  }
}

// ---------------- hysteresis fixpoint (round-4 structure + pend gate) ----------------
__device__ __forceinline__ u64 ks_flood(u64 g, u64 P){
  u64 p1 = P, g1 = g;
  g1 |= p1 & (g1 << 1);  p1 &= (p1 << 1);
  g1 |= p1 & (g1 << 2);  p1 &= (p1 << 2);
  g1 |= p1 & (g1 << 4);  p1 &= (p1 << 4);
  g1 |= p1 & (g1 << 8);  p1 &= (p1 << 8);
  g1 |= p1 & (g1 << 16); p1 &= (p1 << 16);
  g1 |= p1 & (g1 << 32);
  u64 p2 = P, g2 = g;
  g2 |= p2 & (g2 >> 1);  p2 &= (p2 >> 1);
  g2 |= p2 & (g2 >> 2);  p2 &= (p2 >> 2);
  g2 |= p2 & (g2 >> 4);  p2 &= (p2 >> 4);
  g2 |= p2 & (g2 >> 8);  p2 &= (p2 >> 8);
  g2 |= p2 & (g2 >> 16); p2 &= (p2 >> 16);
  g2 |= p2 & (g2 >> 32);
  return g1 | g2;
}

#define HROW(m, l, r_) ((m) | ((m)<<1) | ((m)>>1) | ((l)>>63) | ((r_)<<63))

#define UPD(i) do{ \
    u64 pend = Pr[i] & ~Sr[i]; \
    if (pend){ \
      u64 Sv = Sr[i]; \
      int r = r0 + (i); \
      u64 mu = ((i) > 0) ? Sr[(i)-1] : (r > 0   ? sS[(r-1)*9+w] : 0ull); \
      u64 md = ((i) < 7) ? Sr[(i)+1] : (r < 511 ? sS[(r+1)*9+w] : 0ull); \
      u64 lu = (left  && r > 0)   ? sS[(r-1)*9+w-1] : 0ull; \
      u64 ru = (right && r > 0)   ? sS[(r-1)*9+w+1] : 0ull; \
      u64 lm = left  ? sS[r*9+w-1] : 0ull; \
      u64 rm = right ? sS[r*9+w+1] : 0ull; \
      u64 ldn= (left  && r < 511) ? sS[(r+1)*9+w-1] : 0ull; \
      u64 rdn= (right && r < 511) ? sS[(r+1)*9+w+1] : 0ull; \
      u64 nb = HROW(mu,lu,ru) | HROW(Sv,lm,rm) | HROW(md,ldn,rdn); \
      u64 g = Sv | (Pr[i] & nb); \
      if (g != Sv){ \
        u64 ns = ks_flood(g, Pr[i]); \
        Sr[i] = ns; sS[r*9+w] = ns; changed = true; \
      } \
    } \
  } while(0)

__global__ void __launch_bounds__(512) k_hyst(const u64* __restrict__ A, u64* __restrict__ S)
{
  __shared__ u64 sS[512*9];   // stride 9: breaks 8-way bank aliasing
  int img = blockIdx.x;
  const u64* gA = A + img * 4096;
  u64*       gS = S + img * 4096;
  int tid = threadIdx.x;
  for (int i = tid; i < 4096; i += 512)
    sS[(i>>3)*9 + (i&7)] = gS[i];
  __syncthreads();
  int  w     = tid & 7;
  int  r0    = (tid >> 3) << 3;
  bool left  = (w > 0), right = (w < 7);
  u64 Sr[8], Pr[8];
  #pragma unroll
  for (int i = 0; i < 8; i++){
    Sr[i] = sS[(r0+i)*9 + w];
    Pr[i] = gA[(r0+i)*8 + w] | Sr[i];
  }
  for (;;){
    bool changed = false;
    #pragma unroll 1
    for (int rep = 0; rep < 2; rep++){
      #pragma unroll
      for (int i = 0; i < 8; i++) UPD(i);
      #pragma unroll
      for (int i = 7; i >= 0; i--) UPD(i);
    }
    if (!__syncthreads_or(changed ? 1 : 0)) break;
  }
  #pragma unroll
  for (int i = 0; i < 8; i++) gS[(r0+i)*8 + w] = Sr[i];
}

// ---------------- fused 11-tap separable blur from bitmask + min/max partials ----------------
__global__ void __launch_bounds__(256) k_b11(const u64* __restrict__ S, float* __restrict__ out,
                                             float2* __restrict__ part)
{
#pragma clang fp contract(off)
  __shared__ u64 wds[74][3];
  __shared__ float hb[74][64];
  __shared__ float smn[4], smx[4];
  int b = blockIdx.x;
  int img = b >> 6;
  int t = b & 63;
  int y0 = (t >> 3) << 6;
  int tx = t & 7;
  int x0 = tx << 6;
  int tid = threadIdx.x;
  float g[11]; { float s=0.0f; for(int i=0;i<11;i++){ float tt=(float)i-5.0f; g[i]=expf(-(tt*tt)/4.5f); s+=g[i]; } for(int i=0;i<11;i++) g[i]/=s; }
  // load mask words: rows reflect-mapped (hblur of reflected row == reflected row of hblur'd image)
  for (int i = tid; i < 74*3; i += 256){
    int j = i/3, widx = i - j*3;
    int gy = refl(y0 - 5 + j, HH);
    int gw = tx - 1 + widx;
    wds[j][widx] = (gw >= 0 && gw < 8) ? S[img*4096 + gy*8 + gw] : 0ull;
  }
  __syncthreads();
  // horizontal pass (same tap order as unfused k_b11h)
  for (int i = tid; i < 74*64; i += 256){
    int j = i >> 6, c = i & 63;
    float acc = 0.0f;
    for (int k = 0; k < 11; k++){
      int xx = refl(x0 + c + k - 5, WW);
      int widx = (xx >> 6) - tx + 1;
      float bv = (float)((wds[j][widx] >> (xx & 63)) & 1ull);
      acc += g[k] * bv;
    }
    hb[j][c] = acc;
  }
  __syncthreads();
  // vertical pass + fused per-block min/max
  float mn = 3.4e38f, mx = -3.4e38f;
  float* ob = out + (size_t)img*HW;
  for (int i = tid; i < 4096; i += 256){
    int y = i >> 6, c = i & 63;
    float acc = 0.0f;
    for (int k = 0; k < 11; k++) acc += g[k] * hb[y + k][c];
    ob[(y0 + y)*WW + x0 + c] = acc;
    mn = fminf(mn, acc); mx = fmaxf(mx, acc);
  }
  for (int off = 32; off >= 1; off >>= 1){
    mn = fminf(mn, __shfl_down(mn, off));
    mx = fmaxf(mx, __shfl_down(mx, off));
  }
  int wv = tid >> 6, ln = tid & 63;
  if (ln == 0){ smn[wv] = mn; smx[wv] = mx; }
  __syncthreads();
  if (tid == 0){
    part[b] = make_float2(fminf(fminf(smn[0],smn[1]),fminf(smn[2],smn[3])),
                          fmaxf(fmaxf(smx[0],smx[1]),fmaxf(smx[2],smx[3])));
  }
}

// reduce 64 per-block partials per image -> stats (one 64-thread block per image)
__global__ void k_edred(const float2* __restrict__ part, uint32_t* __restrict__ stats){
  int img = blockIdx.x;
  int ln = threadIdx.x;
  float2 v = part[img*64 + ln];
  float mn = v.x, mx = v.y;
  for (int off = 32; off >= 1; off >>= 1){
    mn = fminf(mn, __shfl_down(mn, off));
    mx = fmaxf(mx, __shfl_down(mx, off));
  }
  if (ln == 0){
    stats[img*4+0] = __float_as_uint(mn);
    stats[img*4+1] = __float_as_uint(mx);
  }
}

// ---------------- fuse: normalize both maps, sigmoid ----------------
__global__ void k_final(const float* __restrict__ ed, const uint16_t* __restrict__ comb,
                        const uint32_t* __restrict__ hist, const uint32_t* __restrict__ stats,
                        const float* __restrict__ alpha, const float* __restrict__ beta,
                        float* __restrict__ out)
{
#pragma clang fp contract(off)
  int idx = blockIdx.x * 256 + threadIdx.x;
  int img = idx >> 18;
  float a = alpha[0], b = beta[0];
  float mne = __uint_as_float(stats[img*4+0]);
  float mxe = __uint_as_float(stats[img*4+1]);
  float mns = __uint_as_float(stats[img*4+2]);
  float mxs = __uint_as_float(stats[img*4+3]);
  float e  = ed[idx];
  float sp = -logf((float)hist[img*NBINS + comb[idx]] / 262144.0f + 1e-9f);
  float en = (e  - mne) / (mxe - mne + 1e-9f);
  float sn = (sp - mns) / (mxs - mns + 1e-9f);
  float f  = a*en + b*sn;
  out[idx] = 1.0f / (1.0f + expf(-f));
}

extern "C" void kernel_launch(void* const* d_in, const int* in_sizes, int n_in,
                              void* d_out, int out_size, void* d_ws, size_t ws_size,
                              hipStream_t stream)
{
  const float* x     = (const float*)d_in[0];
  const float* mean  = (const float*)d_in[1];
  const float* stdv  = (const float*)d_in[2];
  const float* alpha = (const float*)d_in[3];
  const float* beta  = (const float*)d_in[4];
  float* out = (float*)d_out;

  char* ws = (char*)d_ws;
  float*    gray  = (float*)ws;                                   // 16 MB
  uint16_t* comb  = (uint16_t*)(ws + (16u << 20));                // 8 MB
  float2*   part  = (float2*)(ws + (24u << 20));                  // 8 KB
  uint32_t* hist  = (uint32_t*)(ws + (28u << 20));                // 256 KB
  u64*      Ab    = (u64*)(ws + (28u << 20) + (1u << 18));               // 512 KB
  u64*      Sb    = (u64*)(ws + (28u << 20) + (1u << 18) + (1u << 19));  // 512 KB
  uint32_t* stats = (uint32_t*)(ws + (28u << 20) + (1u << 18) + (2u << 19));  // 256 B

  hipLaunchKernelGGL(k_zero,  dim3(64),    dim3(256), 0, stream, (uint4*)hist);
  hipLaunchKernelGGL(k_prep,  dim3(1024),  dim3(256), 0, stream, x, mean, stdv, gray, comb, hist);
  hipLaunchKernelGGL(k_spb,   dim3(NB),    dim3(256), 0, stream, hist, stats);
  hipLaunchKernelGGL(k_canny, dim3(1024),  dim3(256), 0, stream, gray, Ab, Sb);
  hipLaunchKernelGGL(k_hyst,  dim3(NB),    dim3(512), 0, stream, Ab, Sb);
  hipLaunchKernelGGL(k_b11,   dim3(1024),  dim3(256), 0, stream, Sb, out, part);
  hipLaunchKernelGGL(k_edred, dim3(NB),    dim3(64),  0, stream, part, stats);
  hipLaunchKernelGGL(k_final, dim3(16384), dim3(256), 0, stream, out, comb, hist, stats, alpha, beta, out);
}

// Round 7
// 158.141 us; speedup vs baseline: 2.4923x; 1.0122x over previous
//
#include <hip/hip_runtime.h>
#include <stdint.h>

#define NB 16
#define HH 512
#define WW 512
#define HW (HH*WW)          // 262144
#define NBINS 4096

typedef unsigned long long u64;

__device__ __forceinline__ float clip01(float v){ return fminf(fmaxf(v, 0.0f), 1.0f); }
__device__ __forceinline__ int refl(int i, int n){ if (i < 0) i = -i; if (i >= n) i = 2*n - 2 - i; return i; }
__device__ __forceinline__ int clampi(int i, int lo, int hi){ return i < lo ? lo : (i > hi ? hi : i); }

// ---------------- zero the histogram ----------------
__global__ void k_zero(uint4* __restrict__ hist4){
  int idx = blockIdx.x * 256 + threadIdx.x;    // 64 x 256 = 16384 uint4 = 256 KB
  hist4[idx] = make_uint4(0u, 0u, 0u, 0u);
}

// ---------------- denorm + gray + quantized bins + histogram ----------------
__global__ void k_prep(const float* __restrict__ x, const float* __restrict__ mean,
                       const float* __restrict__ stdv, float* __restrict__ gray,
                       uint16_t* __restrict__ comb, uint32_t* __restrict__ hist)
{
#pragma clang fp contract(off)
  __shared__ uint32_t h[NBINS];
  for (int i = threadIdx.x; i < NBINS; i += 256) h[i] = 0u;
  __syncthreads();
  int img  = blockIdx.x >> 6;
  int base = (blockIdx.x & 63) * 4096;
  float m0 = mean[0], m1 = mean[1], m2 = mean[2];
  float s0 = stdv[0], s1 = stdv[1], s2 = stdv[2];
  const float* xb = x + (size_t)img * 3 * HW;
  float*     gb   = gray + (size_t)img*HW;
  uint16_t*  cb   = comb + (size_t)img*HW;
  #pragma unroll
  for (int it = 0; it < 4; it++){
    int f4 = it*256 + threadIdx.x;
    int p  = base + f4*4;
    float4 r = *(const float4*)(xb + p);
    float4 g = *(const float4*)(xb + HW + p);
    float4 b = *(const float4*)(xb + 2*HW + p);
    float xr[4] = {r.x, r.y, r.z, r.w};
    float xg[4] = {g.x, g.y, g.z, g.w};
    float xbl[4] = {b.x, b.y, b.z, b.w};
    float gy[4]; uint16_t cc[4];
    #pragma unroll
    for (int j = 0; j < 4; j++){
      float cr = clip01(xr[j]*s0 + m0);
      float cg = clip01(xg[j]*s1 + m1);
      float cbv= clip01(xbl[j]*s2 + m2);
      gy[j] = 0.299f*cr + 0.587f*cg + 0.114f*cbv;
      int c = ((int)rintf(cr*15.0f))*256 + ((int)rintf(cg*15.0f))*16 + (int)rintf(cbv*15.0f);
      cc[j] = (uint16_t)c;
      atomicAdd(&h[c], 1u);
    }
    *(float4*)(gb + p) = make_float4(gy[0], gy[1], gy[2], gy[3]);
    ushort4 cv; cv.x = cc[0]; cv.y = cc[1]; cv.z = cc[2]; cv.w = cc[3];
    *(ushort4*)(cb + p) = cv;
  }
  __syncthreads();
  uint32_t* gh = hist + img * NBINS;
  for (int i = threadIdx.x; i < NBINS; i += 256){ uint32_t v = h[i]; if (v) atomicAdd(&gh[i], v); }
}

// ---------------- sparsity min/max from histogram ----------------
__global__ void k_spb(const uint32_t* __restrict__ hist, uint32_t* __restrict__ stats){
  int img = blockIdx.x;
  uint32_t mx = 0u, mn = 0xFFFFFFFFu;
  for (int i = threadIdx.x; i < NBINS; i += 256){
    uint32_t c = hist[img*NBINS + i];
    if (c > mx) mx = c;
    if (c > 0u && c < mn) mn = c;
  }
  __shared__ uint32_t rmx[256], rmn[256];
  rmx[threadIdx.x] = mx; rmn[threadIdx.x] = mn;
  __syncthreads();
  for (int s = 128; s > 0; s >>= 1){
    if (threadIdx.x < (unsigned)s){
      rmx[threadIdx.x] = max(rmx[threadIdx.x], rmx[threadIdx.x + s]);
      rmn[threadIdx.x] = min(rmn[threadIdx.x], rmn[threadIdx.x + s]);
    }
    __syncthreads();
  }
  if (threadIdx.x == 0){
    float sp_min = -logf((float)rmx[0] / 262144.0f + 1e-9f);
    float sp_max = -logf((float)rmn[0] / 262144.0f + 1e-9f);
    stats[img*4+2] = __float_as_uint(sp_min);
    stats[img*4+3] = __float_as_uint(sp_max);
  }
}

// ---------------- fused blur5 + sobel + NMS + threshold -> bitmasks ----------------
// 64x64 output tile per block. Blur: register-window column sweep, identical
// tap order to the verified unfused kernel. Direction: branchless octant
// classification replacing atan2f (boundary cases verified vs round-half-even).
__global__ void __launch_bounds__(256) k_canny(const float* __restrict__ gray,
                                               u64* __restrict__ A, u64* __restrict__ Sb)
{
#pragma clang fp contract(off)
  __shared__ float ubuf[72*73];      // gray (72x72, stride 73) then mag (66x66, stride 67)
  __shared__ float blr[68*69];       // blurred (68x68, stride 69)
  __shared__ uint8_t sdir[64*64];
  int b = blockIdx.x;
  int img = b >> 6;
  int t = b & 63;
  int y0 = (t >> 3) << 6;
  int x0 = (t & 7) << 6;
  const float* gb = gray + (size_t)img*HW;
  int tid = threadIdx.x;
  float g5[5]; { float s=0.0f; for(int i=0;i<5;i++){ float tt=(float)i-2.0f; g5[i]=expf(-(tt*tt)/2.0f); s+=g5[i]; } for(int i=0;i<5;i++) g5[i]/=s; }
  // S1: load gray tile with reflect halo 4
  for (int i = tid; i < 72*72; i += 256){
    int ly = i/72, lx = i - ly*72;
    int gy = refl(y0 - 4 + ly, HH);
    int gx = refl(x0 - 4 + lx, WW);
    ubuf[ly*73 + lx] = gb[gy*WW + gx];
  }
  __syncthreads();
  // S2: 5x5 blur, register-window column sweep (68 cols x 4 chunks of 17 rows)
  for (int task = tid; task < 272; task += 256){
    int lx = task % 68;
    int ly = (task / 68) * 17;
    float w[5][5];
    #pragma unroll
    for (int j = 0; j < 4; j++)
      #pragma unroll
      for (int k = 0; k < 5; k++)
        w[j][k] = ubuf[(ly+j)*73 + lx + k];
    #pragma unroll
    for (int s = 0; s < 17; s++){
      #pragma unroll
      for (int k = 0; k < 5; k++) w[4][k] = ubuf[(ly+s+4)*73 + lx + k];
      float acc = 0.0f;
      #pragma unroll
      for (int ky = 0; ky < 5; ky++)
        #pragma unroll
        for (int kx = 0; kx < 5; kx++)
          acc += (g5[ky]*g5[kx]) * w[ky][kx];
      blr[(ly+s)*69 + lx] = acc;
      #pragma unroll
      for (int j = 0; j < 4; j++)
        #pragma unroll
        for (int k = 0; k < 5; k++) w[j][k] = w[j+1][k];
    }
  }
  __syncthreads();
  // S3: sobel (clamp pad) -> mag halo 1 + dir at center; ubuf becomes mag
  for (int i = tid; i < 66*66; i += 256){
    int ly = i/66, lx = i - ly*66;
    int Y = y0 - 1 + ly, X = x0 - 1 + lx;
    float m = 0.0f;
    if (Y >= 0 && Y < HH && X >= 0 && X < WW){
      float v[3][3];
      for (int dy = 0; dy < 3; dy++){
        int Yl = clampi(Y + dy - 1, 0, HH-1) - (y0 - 2);
        for (int dx = 0; dx < 3; dx++){
          int Xl = clampi(X + dx - 1, 0, WW-1) - (x0 - 2);
          v[dy][dx] = blr[Yl*69 + Xl];
        }
      }
      float gx = (v[0][2] - v[0][0]) + 2.0f*(v[1][2] - v[1][0]) + (v[2][2] - v[2][0]);
      float gy = (v[2][0] + 2.0f*v[2][1] + v[2][2]) - (v[0][0] + 2.0f*v[0][1] + v[0][2]);
      m = sqrtf(gx*gx + gy*gy + 1e-6f);
      if (ly >= 1 && ly <= 64 && lx >= 1 && lx <= 64){
        // octant of rint(atan2(gy,gx)*180/pi / 45) mod 8, via comparisons.
        // boundaries (half-even): +-22.5/+-157.5 -> horizontal(0/4) [<=],
        // +-67.5/+-112.5 -> vertical(2/6) [>=]; atan2(0,0)=0 -> d=0.
        float ax = fabsf(gx), ay = fabsf(gy);
        int d;
        if (ay <= 0.41421356237309503f*ax) d = (gx >= 0.0f) ? 0 : 4;
        else if (ay >= 2.4142135623730951f*ax) d = (gy > 0.0f) ? 2 : 6;
        else if (gx > 0.0f) d = (gy > 0.0f) ? 1 : 7;
        else d = (gy > 0.0f) ? 3 : 5;
        sdir[(ly-1)*64 + (lx-1)] = (uint8_t)d;
      }
    }
    ubuf[ly*67 + lx] = m;
  }
  __syncthreads();
  // S4: NMS + double threshold + ballot (tile width 64 = one mask word per row)
  const int OY[8] = {0,1,1,1,0,-1,-1,-1};
  const int OX[8] = {1,1,0,-1,-1,-1,0,1};
  int lane = tid & 63, wv = tid >> 6;
  for (int j = 0; j < 16; j++){
    int y = j*4 + wv;
    int x = lane;
    float m = ubuf[(y+1)*67 + (x+1)];
    int d  = sdir[y*64 + x];
    int d2 = (d + 4) & 7;
    float mp = 0.0f, mn = 0.0f;
    { int yy=y+OY[d],  xx=x+OX[d];  int gy=y0+yy, gx=x0+xx; if(gy>=0&&gy<HH&&gx>=0&&gx<WW) mp = ubuf[(yy+1)*67 + (xx+1)]; }
    { int yy=y+OY[d2], xx=x+OX[d2]; int gy=y0+yy, gx=x0+xx; if(gy>=0&&gy<HH&&gx>=0&&gx<WW) mn = ubuf[(yy+1)*67 + (xx+1)]; }
    bool keep = ((m - mp) > 0.0f) && ((m - mn) > 0.0f);
    float mf = keep ? m : 0.0f;
    bool strong = mf > 0.2f;
    bool weak   = (mf > 0.1f) && !strong;
    u64 wb = __ballot(weak);
    u64 sb = __ballot(strong);
    if (lane == 0){
      int gy = y0 + y;
      A [img*4096 + gy*8 + (x0>>6)] = wb;
      Sb[img*4096 + gy*8 + (x0>>6)] = sb;
    }
  }
}

// ---------------- hysteresis fixpoint (round-4 structure + pend gate) ----------------
__device__ __forceinline__ u64 ks_flood(u64 g, u64 P){
  u64 p1 = P, g1 = g;
  g1 |= p1 & (g1 << 1);  p1 &= (p1 << 1);
  g1 |= p1 & (g1 << 2);  p1 &= (p1 << 2);
  g1 |= p1 & (g1 << 4);  p1 &= (p1 << 4);
  g1 |= p1 & (g1 << 8);  p1 &= (p1 << 8);
  g1 |= p1 & (g1 << 16); p1 &= (p1 << 16);
  g1 |= p1 & (g1 << 32);
  u64 p2 = P, g2 = g;
  g2 |= p2 & (g2 >> 1);  p2 &= (p2 >> 1);
  g2 |= p2 & (g2 >> 2);  p2 &= (p2 >> 2);
  g2 |= p2 & (g2 >> 4);  p2 &= (p2 >> 4);
  g2 |= p2 & (g2 >> 8);  p2 &= (p2 >> 8);
  g2 |= p2 & (g2 >> 16); p2 &= (p2 >> 16);
  g2 |= p2 & (g2 >> 32);
  return g1 | g2;
}

#define HROW(m, l, r_) ((m) | ((m)<<1) | ((m)>>1) | ((l)>>63) | ((r_)<<63))

#define UPD(i) do{ \
    u64 pend = Pr[i] & ~Sr[i]; \
    if (pend){ \
      u64 Sv = Sr[i]; \
      int r = r0 + (i); \
      u64 mu = ((i) > 0) ? Sr[(i)-1] : (r > 0   ? sS[(r-1)*9+w] : 0ull); \
      u64 md = ((i) < 7) ? Sr[(i)+1] : (r < 511 ? sS[(r+1)*9+w] : 0ull); \
      u64 lu = (left  && r > 0)   ? sS[(r-1)*9+w-1] : 0ull; \
      u64 ru = (right && r > 0)   ? sS[(r-1)*9+w+1] : 0ull; \
      u64 lm = left  ? sS[r*9+w-1] : 0ull; \
      u64 rm = right ? sS[r*9+w+1] : 0ull; \
      u64 ldn= (left  && r < 511) ? sS[(r+1)*9+w-1] : 0ull; \
      u64 rdn= (right && r < 511) ? sS[(r+1)*9+w+1] : 0ull; \
      u64 nb = HROW(mu,lu,ru) | HROW(Sv,lm,rm) | HROW(md,ldn,rdn); \
      u64 g = Sv | (Pr[i] & nb); \
      if (g != Sv){ \
        u64 ns = ks_flood(g, Pr[i]); \
        Sr[i] = ns; sS[r*9+w] = ns; changed = true; \
      } \
    } \
  } while(0)

__global__ void __launch_bounds__(512) k_hyst(const u64* __restrict__ A, u64* __restrict__ S)
{
  __shared__ u64 sS[512*9];   // stride 9: breaks 8-way bank aliasing
  int img = blockIdx.x;
  const u64* gA = A + img * 4096;
  u64*       gS = S + img * 4096;
  int tid = threadIdx.x;
  for (int i = tid; i < 4096; i += 512)
    sS[(i>>3)*9 + (i&7)] = gS[i];
  __syncthreads();
  int  w     = tid & 7;
  int  r0    = (tid >> 3) << 3;
  bool left  = (w > 0), right = (w < 7);
  u64 Sr[8], Pr[8];
  #pragma unroll
  for (int i = 0; i < 8; i++){
    Sr[i] = sS[(r0+i)*9 + w];
    Pr[i] = gA[(r0+i)*8 + w] | Sr[i];
  }
  for (;;){
    bool changed = false;
    #pragma unroll 1
    for (int rep = 0; rep < 2; rep++){
      #pragma unroll
      for (int i = 0; i < 8; i++) UPD(i);
      #pragma unroll
      for (int i = 7; i >= 0; i--) UPD(i);
    }
    if (!__syncthreads_or(changed ? 1 : 0)) break;
  }
  #pragma unroll
  for (int i = 0; i < 8; i++) gS[(r0+i)*8 + w] = Sr[i];
}

// ---------------- fused 11-tap separable blur from bitmask + min/max partials ----------------
__global__ void __launch_bounds__(256) k_b11(const u64* __restrict__ S, float* __restrict__ out,
                                             float2* __restrict__ part)
{
#pragma clang fp contract(off)
  __shared__ u64 wds[74][3];
  __shared__ float hb[74][64];
  __shared__ float smn[4], smx[4];
  int b = blockIdx.x;
  int img = b >> 6;
  int t = b & 63;
  int y0 = (t >> 3) << 6;
  int tx = t & 7;
  int x0 = tx << 6;
  int tid = threadIdx.x;
  float g[11]; { float s=0.0f; for(int i=0;i<11;i++){ float tt=(float)i-5.0f; g[i]=expf(-(tt*tt)/4.5f); s+=g[i]; } for(int i=0;i<11;i++) g[i]/=s; }
  for (int i = tid; i < 74*3; i += 256){
    int j = i/3, widx = i - j*3;
    int gy = refl(y0 - 5 + j, HH);
    int gw = tx - 1 + widx;
    wds[j][widx] = (gw >= 0 && gw < 8) ? S[img*4096 + gy*8 + gw] : 0ull;
  }
  __syncthreads();
  for (int i = tid; i < 74*64; i += 256){
    int j = i >> 6, c = i & 63;
    float acc = 0.0f;
    for (int k = 0; k < 11; k++){
      int xx = refl(x0 + c + k - 5, WW);
      int widx = (xx >> 6) - tx + 1;
      float bv = (float)((wds[j][widx] >> (xx & 63)) & 1ull);
      acc += g[k] * bv;
    }
    hb[j][c] = acc;
  }
  __syncthreads();
  float mn = 3.4e38f, mx = -3.4e38f;
  float* ob = out + (size_t)img*HW;
  for (int i = tid; i < 4096; i += 256){
    int y = i >> 6, c = i & 63;
    float acc = 0.0f;
    for (int k = 0; k < 11; k++) acc += g[k] * hb[y + k][c];
    ob[(y0 + y)*WW + x0 + c] = acc;
    mn = fminf(mn, acc); mx = fmaxf(mx, acc);
  }
  for (int off = 32; off >= 1; off >>= 1){
    mn = fminf(mn, __shfl_down(mn, off));
    mx = fmaxf(mx, __shfl_down(mx, off));
  }
  int wv = tid >> 6, ln = tid & 63;
  if (ln == 0){ smn[wv] = mn; smx[wv] = mx; }
  __syncthreads();
  if (tid == 0){
    part[b] = make_float2(fminf(fminf(smn[0],smn[1]),fminf(smn[2],smn[3])),
                          fmaxf(fmaxf(smx[0],smx[1]),fmaxf(smx[2],smx[3])));
  }
}

// reduce 64 per-block partials per image -> stats (one 64-thread block per image)
__global__ void k_edred(const float2* __restrict__ part, uint32_t* __restrict__ stats){
  int img = blockIdx.x;
  int ln = threadIdx.x;
  float2 v = part[img*64 + ln];
  float mn = v.x, mx = v.y;
  for (int off = 32; off >= 1; off >>= 1){
    mn = fminf(mn, __shfl_down(mn, off));
    mx = fmaxf(mx, __shfl_down(mx, off));
  }
  if (ln == 0){
    stats[img*4+0] = __float_as_uint(mn);
    stats[img*4+1] = __float_as_uint(mx);
  }
}

// ---------------- fuse: normalize both maps, sigmoid ----------------
__global__ void k_final(const float* __restrict__ ed, const uint16_t* __restrict__ comb,
                        const uint32_t* __restrict__ hist, const uint32_t* __restrict__ stats,
                        const float* __restrict__ alpha, const float* __restrict__ beta,
                        float* __restrict__ out)
{
#pragma clang fp contract(off)
  int idx = blockIdx.x * 256 + threadIdx.x;
  int img = idx >> 18;
  float a = alpha[0], b = beta[0];
  float mne = __uint_as_float(stats[img*4+0]);
  float mxe = __uint_as_float(stats[img*4+1]);
  float mns = __uint_as_float(stats[img*4+2]);
  float mxs = __uint_as_float(stats[img*4+3]);
  float e  = ed[idx];
  float sp = -logf((float)hist[img*NBINS + comb[idx]] / 262144.0f + 1e-9f);
  float en = (e  - mne) / (mxe - mne + 1e-9f);
  float sn = (sp - mns) / (mxs - mns + 1e-9f);
  float f  = a*en + b*sn;
  out[idx] = 1.0f / (1.0f + expf(-f));
}

extern "C" void kernel_launch(void* const* d_in, const int* in_sizes, int n_in,
                              void* d_out, int out_size, void* d_ws, size_t ws_size,
                              hipStream_t stream)
{
  const float* x     = (const float*)d_in[0];
  const float* mean  = (const float*)d_in[1];
  const float* stdv  = (const float*)d_in[2];
  const float* alpha = (const float*)d_in[3];
  const float* beta  = (const float*)d_in[4];
  float* out = (float*)d_out;

  char* ws = (char*)d_ws;
  float*    gray  = (float*)ws;                                   // 16 MB
  uint16_t* comb  = (uint16_t*)(ws + (16u << 20));                // 8 MB
  float2*   part  = (float2*)(ws + (24u << 20));                  // 8 KB
  uint32_t* hist  = (uint32_t*)(ws + (28u << 20));                // 256 KB
  u64*      Ab    = (u64*)(ws + (28u << 20) + (1u << 18));               // 512 KB
  u64*      Sb    = (u64*)(ws + (28u << 20) + (1u << 18) + (1u << 19));  // 512 KB
  uint32_t* stats = (uint32_t*)(ws + (28u << 20) + (1u << 18) + (2u << 19));  // 256 B

  hipLaunchKernelGGL(k_zero,  dim3(64),    dim3(256), 0, stream, (uint4*)hist);
  hipLaunchKernelGGL(k_prep,  dim3(1024),  dim3(256), 0, stream, x, mean, stdv, gray, comb, hist);
  hipLaunchKernelGGL(k_spb,   dim3(NB),    dim3(256), 0, stream, hist, stats);
  hipLaunchKernelGGL(k_canny, dim3(1024),  dim3(256), 0, stream, gray, Ab, Sb);
  hipLaunchKernelGGL(k_hyst,  dim3(NB),    dim3(512), 0, stream, Ab, Sb);
  hipLaunchKernelGGL(k_b11,   dim3(1024),  dim3(256), 0, stream, Sb, out, part);
  hipLaunchKernelGGL(k_edred, dim3(NB),    dim3(64),  0, stream, part, stats);
  hipLaunchKernelGGL(k_final, dim3(16384), dim3(256), 0, stream, out, comb, hist, stats, alpha, beta, out);
}

// Round 8
// 134.779 us; speedup vs baseline: 2.9243x; 1.1733x over previous
//
#include <hip/hip_runtime.h>
#include <stdint.h>

#define NB 16
#define HH 512
#define WW 512
#define HW (HH*WW)          // 262144
#define NBINS 4096

typedef unsigned long long u64;

__device__ __forceinline__ float clip01(float v){ return fminf(fmaxf(v, 0.0f), 1.0f); }
__device__ __forceinline__ int refl(int i, int n){ if (i < 0) i = -i; if (i >= n) i = 2*n - 2 - i; return i; }
__device__ __forceinline__ int clampi(int i, int lo, int hi){ return i < lo ? lo : (i > hi ? hi : i); }

// ---------------- zero the histogram ----------------
__global__ void k_zero(uint4* __restrict__ hist4){
  int idx = blockIdx.x * 256 + threadIdx.x;    // 64 x 256 = 16384 uint4 = 256 KB
  hist4[idx] = make_uint4(0u, 0u, 0u, 0u);
}

// ---------------- denorm + gray + quantized bins + histogram ----------------
__global__ void k_prep(const float* __restrict__ x, const float* __restrict__ mean,
                       const float* __restrict__ stdv, float* __restrict__ gray,
                       uint16_t* __restrict__ comb, uint32_t* __restrict__ hist)
{
#pragma clang fp contract(off)
  __shared__ uint32_t h[NBINS];
  for (int i = threadIdx.x; i < NBINS; i += 256) h[i] = 0u;
  __syncthreads();
  int img  = blockIdx.x >> 6;
  int base = (blockIdx.x & 63) * 4096;
  float m0 = mean[0], m1 = mean[1], m2 = mean[2];
  float s0 = stdv[0], s1 = stdv[1], s2 = stdv[2];
  const float* xb = x + (size_t)img * 3 * HW;
  float*     gb   = gray + (size_t)img*HW;
  uint16_t*  cb   = comb + (size_t)img*HW;
  #pragma unroll
  for (int it = 0; it < 4; it++){
    int f4 = it*256 + threadIdx.x;
    int p  = base + f4*4;
    float4 r = *(const float4*)(xb + p);
    float4 g = *(const float4*)(xb + HW + p);
    float4 b = *(const float4*)(xb + 2*HW + p);
    float xr[4] = {r.x, r.y, r.z, r.w};
    float xg[4] = {g.x, g.y, g.z, g.w};
    float xbl[4] = {b.x, b.y, b.z, b.w};
    float gy[4]; uint16_t cc[4];
    #pragma unroll
    for (int j = 0; j < 4; j++){
      float cr = clip01(xr[j]*s0 + m0);
      float cg = clip01(xg[j]*s1 + m1);
      float cbv= clip01(xbl[j]*s2 + m2);
      gy[j] = 0.299f*cr + 0.587f*cg + 0.114f*cbv;
      int c = ((int)rintf(cr*15.0f))*256 + ((int)rintf(cg*15.0f))*16 + (int)rintf(cbv*15.0f);
      cc[j] = (uint16_t)c;
      atomicAdd(&h[c], 1u);
    }
    *(float4*)(gb + p) = make_float4(gy[0], gy[1], gy[2], gy[3]);
    ushort4 cv; cv.x = cc[0]; cv.y = cc[1]; cv.z = cc[2]; cv.w = cc[3];
    *(ushort4*)(cb + p) = cv;
  }
  __syncthreads();
  uint32_t* gh = hist + img * NBINS;
  for (int i = threadIdx.x; i < NBINS; i += 256){ uint32_t v = h[i]; if (v) atomicAdd(&gh[i], v); }
}

// ---------------- sparsity min/max from histogram ----------------
__global__ void k_spb(const uint32_t* __restrict__ hist, uint32_t* __restrict__ stats){
  int img = blockIdx.x;
  uint32_t mx = 0u, mn = 0xFFFFFFFFu;
  for (int i = threadIdx.x; i < NBINS; i += 256){
    uint32_t c = hist[img*NBINS + i];
    if (c > mx) mx = c;
    if (c > 0u && c < mn) mn = c;
  }
  __shared__ uint32_t rmx[256], rmn[256];
  rmx[threadIdx.x] = mx; rmn[threadIdx.x] = mn;
  __syncthreads();
  for (int s = 128; s > 0; s >>= 1){
    if (threadIdx.x < (unsigned)s){
      rmx[threadIdx.x] = max(rmx[threadIdx.x], rmx[threadIdx.x + s]);
      rmn[threadIdx.x] = min(rmn[threadIdx.x], rmn[threadIdx.x + s]);
    }
    __syncthreads();
  }
  if (threadIdx.x == 0){
    float sp_min = -logf((float)rmx[0] / 262144.0f + 1e-9f);
    float sp_max = -logf((float)rmn[0] / 262144.0f + 1e-9f);
    stats[img*4+2] = __float_as_uint(sp_min);
    stats[img*4+3] = __float_as_uint(sp_max);
  }
}

// ---------------- fused blur5 + sobel + NMS + threshold -> bitmasks ----------------
// 32x64 output tile per block (LDS 23 KB -> 6 blocks/CU). Arithmetic identical
// to the verified version: same tap order, same octant classification.
__global__ void __launch_bounds__(256) k_canny(const float* __restrict__ gray,
                                               u64* __restrict__ A, u64* __restrict__ Sb)
{
#pragma clang fp contract(off)
  __shared__ float ubuf[40*73];      // gray (40x72, stride 73) then mag (34x66, stride 67)
  __shared__ float blr[36*69];       // blurred (36x68, stride 69)
  __shared__ uint8_t sdir[32*64];
  int b = blockIdx.x;
  int img = b >> 7;
  int t = b & 127;
  int y0 = (t >> 3) << 5;            // 16 y-tiles of 32 rows
  int x0 = (t & 7) << 6;             // 8 x-tiles of 64 cols
  const float* gb = gray + (size_t)img*HW;
  int tid = threadIdx.x;
  float g5[5]; { float s=0.0f; for(int i=0;i<5;i++){ float tt=(float)i-2.0f; g5[i]=expf(-(tt*tt)/2.0f); s+=g5[i]; } for(int i=0;i<5;i++) g5[i]/=s; }
  // S1: load gray tile with reflect halo 4 (40 rows x 72 cols)
  for (int i = tid; i < 40*72; i += 256){
    int ly = i/72, lx = i - ly*72;
    int gy = refl(y0 - 4 + ly, HH);
    int gx = refl(x0 - 4 + lx, WW);
    ubuf[ly*73 + lx] = gb[gy*WW + gx];
  }
  __syncthreads();
  // S2: 5x5 blur, register-window column sweep (68 cols x 4 chunks of 9 rows = 36 rows)
  for (int task = tid; task < 272; task += 256){
    int lx = task % 68;
    int ly = (task / 68) * 9;
    float w[5][5];
    #pragma unroll
    for (int j = 0; j < 4; j++)
      #pragma unroll
      for (int k = 0; k < 5; k++)
        w[j][k] = ubuf[(ly+j)*73 + lx + k];
    #pragma unroll
    for (int s = 0; s < 9; s++){
      #pragma unroll
      for (int k = 0; k < 5; k++) w[4][k] = ubuf[(ly+s+4)*73 + lx + k];
      float acc = 0.0f;
      #pragma unroll
      for (int ky = 0; ky < 5; ky++)
        #pragma unroll
        for (int kx = 0; kx < 5; kx++)
          acc += (g5[ky]*g5[kx]) * w[ky][kx];
      blr[(ly+s)*69 + lx] = acc;
      #pragma unroll
      for (int j = 0; j < 4; j++)
        #pragma unroll
        for (int k = 0; k < 5; k++) w[j][k] = w[j+1][k];
    }
  }
  __syncthreads();
  // S3: sobel (clamp pad) -> mag (34x66) + dir at center (32x64); ubuf becomes mag
  for (int i = tid; i < 34*66; i += 256){
    int ly = i/66, lx = i - ly*66;
    int Y = y0 - 1 + ly, X = x0 - 1 + lx;
    float m = 0.0f;
    if (Y >= 0 && Y < HH && X >= 0 && X < WW){
      float v[3][3];
      for (int dy = 0; dy < 3; dy++){
        int Yl = clampi(Y + dy - 1, 0, HH-1) - (y0 - 2);
        for (int dx = 0; dx < 3; dx++){
          int Xl = clampi(X + dx - 1, 0, WW-1) - (x0 - 2);
          v[dy][dx] = blr[Yl*69 + Xl];
        }
      }
      float gx = (v[0][2] - v[0][0]) + 2.0f*(v[1][2] - v[1][0]) + (v[2][2] - v[2][0]);
      float gy = (v[2][0] + 2.0f*v[2][1] + v[2][2]) - (v[0][0] + 2.0f*v[0][1] + v[0][2]);
      m = sqrtf(gx*gx + gy*gy + 1e-6f);
      if (ly >= 1 && ly <= 32 && lx >= 1 && lx <= 64){
        float ax = fabsf(gx), ay = fabsf(gy);
        int d;
        if (ay <= 0.41421356237309503f*ax) d = (gx >= 0.0f) ? 0 : 4;
        else if (ay >= 2.4142135623730951f*ax) d = (gy > 0.0f) ? 2 : 6;
        else if (gx > 0.0f) d = (gy > 0.0f) ? 1 : 7;
        else d = (gy > 0.0f) ? 3 : 5;
        sdir[(ly-1)*64 + (lx-1)] = (uint8_t)d;
      }
    }
    ubuf[ly*67 + lx] = m;
  }
  __syncthreads();
  // S4: NMS + double threshold + ballot (tile width 64 = one mask word per row)
  const int OY[8] = {0,1,1,1,0,-1,-1,-1};
  const int OX[8] = {1,1,0,-1,-1,-1,0,1};
  int lane = tid & 63, wv = tid >> 6;
  for (int j = 0; j < 8; j++){
    int y = j*4 + wv;
    int x = lane;
    float m = ubuf[(y+1)*67 + (x+1)];
    int d  = sdir[y*64 + x];
    int d2 = (d + 4) & 7;
    float mp = 0.0f, mn = 0.0f;
    { int yy=y+OY[d],  xx=x+OX[d];  int gy=y0+yy, gx=x0+xx; if(gy>=0&&gy<HH&&gx>=0&&gx<WW) mp = ubuf[(yy+1)*67 + (xx+1)]; }
    { int yy=y+OY[d2], xx=x+OX[d2]; int gy=y0+yy, gx=x0+xx; if(gy>=0&&gy<HH&&gx>=0&&gx<WW) mn = ubuf[(yy+1)*67 + (xx+1)]; }
    bool keep = ((m - mp) > 0.0f) && ((m - mn) > 0.0f);
    float mf = keep ? m : 0.0f;
    bool strong = mf > 0.2f;
    bool weak   = (mf > 0.1f) && !strong;
    u64 wb = __ballot(weak);
    u64 sb = __ballot(strong);
    if (lane == 0){
      int gy = y0 + y;
      A [img*4096 + gy*8 + (x0>>6)] = wb;
      Sb[img*4096 + gy*8 + (x0>>6)] = sb;
    }
  }
}

// ---------------- hysteresis fixpoint: 1024 threads, 4 rows/thread ----------------
__device__ __forceinline__ u64 ks_flood(u64 g, u64 P){
  u64 p1 = P, g1 = g;
  g1 |= p1 & (g1 << 1);  p1 &= (p1 << 1);
  g1 |= p1 & (g1 << 2);  p1 &= (p1 << 2);
  g1 |= p1 & (g1 << 4);  p1 &= (p1 << 4);
  g1 |= p1 & (g1 << 8);  p1 &= (p1 << 8);
  g1 |= p1 & (g1 << 16); p1 &= (p1 << 16);
  g1 |= p1 & (g1 << 32);
  u64 p2 = P, g2 = g;
  g2 |= p2 & (g2 >> 1);  p2 &= (p2 >> 1);
  g2 |= p2 & (g2 >> 2);  p2 &= (p2 >> 2);
  g2 |= p2 & (g2 >> 4);  p2 &= (p2 >> 4);
  g2 |= p2 & (g2 >> 8);  p2 &= (p2 >> 8);
  g2 |= p2 & (g2 >> 16); p2 &= (p2 >> 16);
  g2 |= p2 & (g2 >> 32);
  return g1 | g2;
}

#define HROW(m, l, r_) ((m) | ((m)<<1) | ((m)>>1) | ((l)>>63) | ((r_)<<63))

#define UPD(i) do{ \
    u64 pend = Pr[i] & ~Sr[i]; \
    if (pend){ \
      u64 Sv = Sr[i]; \
      int r = r0 + (i); \
      u64 mu = ((i) > 0) ? Sr[(i)-1] : (r > 0   ? sS[(r-1)*9+w] : 0ull); \
      u64 md = ((i) < 3) ? Sr[(i)+1] : (r < 511 ? sS[(r+1)*9+w] : 0ull); \
      u64 lu = (left  && r > 0)   ? sS[(r-1)*9+w-1] : 0ull; \
      u64 ru = (right && r > 0)   ? sS[(r-1)*9+w+1] : 0ull; \
      u64 lm = left  ? sS[r*9+w-1] : 0ull; \
      u64 rm = right ? sS[r*9+w+1] : 0ull; \
      u64 ldn= (left  && r < 511) ? sS[(r+1)*9+w-1] : 0ull; \
      u64 rdn= (right && r < 511) ? sS[(r+1)*9+w+1] : 0ull; \
      u64 nb = HROW(mu,lu,ru) | HROW(Sv,lm,rm) | HROW(md,ldn,rdn); \
      u64 g = Sv | (Pr[i] & nb); \
      if (g != Sv){ \
        u64 ns = ks_flood(g, Pr[i]); \
        Sr[i] = ns; sS[r*9+w] = ns; changed = true; \
      } \
    } \
  } while(0)

__global__ void __launch_bounds__(1024) k_hyst(const u64* __restrict__ A, u64* __restrict__ S)
{
  __shared__ u64 sS[512*9];   // stride 9: breaks 8-way bank aliasing
  int img = blockIdx.x;
  const u64* gA = A + img * 4096;
  u64*       gS = S + img * 4096;
  int tid = threadIdx.x;
  for (int i = tid; i < 4096; i += 1024)
    sS[(i>>3)*9 + (i&7)] = gS[i];
  __syncthreads();
  int  w     = tid & 7;
  int  r0    = (tid >> 3) << 2;     // 4 rows per thread
  bool left  = (w > 0), right = (w < 7);
  u64 Sr[4], Pr[4];
  #pragma unroll
  for (int i = 0; i < 4; i++){
    Sr[i] = sS[(r0+i)*9 + w];
    Pr[i] = gA[(r0+i)*8 + w] | Sr[i];
  }
  for (;;){
    bool changed = false;
    #pragma unroll 1
    for (int rep = 0; rep < 2; rep++){
      #pragma unroll
      for (int i = 0; i < 4; i++) UPD(i);
      #pragma unroll
      for (int i = 3; i >= 0; i--) UPD(i);
    }
    if (!__syncthreads_or(changed ? 1 : 0)) break;
  }
  #pragma unroll
  for (int i = 0; i < 4; i++) gS[(r0+i)*8 + w] = Sr[i];
}

// ---------------- fused 11-tap separable blur from bitmask + min/max partials ----------------
__global__ void __launch_bounds__(256) k_b11(const u64* __restrict__ S, float* __restrict__ out,
                                             float2* __restrict__ part)
{
#pragma clang fp contract(off)
  __shared__ u64 wds[74][3];
  __shared__ float hb[74][64];
  __shared__ float smn[4], smx[4];
  int b = blockIdx.x;
  int img = b >> 6;
  int t = b & 63;
  int y0 = (t >> 3) << 6;
  int tx = t & 7;
  int x0 = tx << 6;
  int tid = threadIdx.x;
  float g[11]; { float s=0.0f; for(int i=0;i<11;i++){ float tt=(float)i-5.0f; g[i]=expf(-(tt*tt)/4.5f); s+=g[i]; } for(int i=0;i<11;i++) g[i]/=s; }
  for (int i = tid; i < 74*3; i += 256){
    int j = i/3, widx = i - j*3;
    int gy = refl(y0 - 5 + j, HH);
    int gw = tx - 1 + widx;
    wds[j][widx] = (gw >= 0 && gw < 8) ? S[img*4096 + gy*8 + gw] : 0ull;
  }
  __syncthreads();
  for (int i = tid; i < 74*64; i += 256){
    int j = i >> 6, c = i & 63;
    float acc = 0.0f;
    for (int k = 0; k < 11; k++){
      int xx = refl(x0 + c + k - 5, WW);
      int widx = (xx >> 6) - tx + 1;
      float bv = (float)((wds[j][widx] >> (xx & 63)) & 1ull);
      acc += g[k] * bv;
    }
    hb[j][c] = acc;
  }
  __syncthreads();
  float mn = 3.4e38f, mx = -3.4e38f;
  float* ob = out + (size_t)img*HW;
  for (int i = tid; i < 4096; i += 256){
    int y = i >> 6, c = i & 63;
    float acc = 0.0f;
    for (int k = 0; k < 11; k++) acc += g[k] * hb[y + k][c];
    ob[(y0 + y)*WW + x0 + c] = acc;
    mn = fminf(mn, acc); mx = fmaxf(mx, acc);
  }
  for (int off = 32; off >= 1; off >>= 1){
    mn = fminf(mn, __shfl_down(mn, off));
    mx = fmaxf(mx, __shfl_down(mx, off));
  }
  int wv = tid >> 6, ln = tid & 63;
  if (ln == 0){ smn[wv] = mn; smx[wv] = mx; }
  __syncthreads();
  if (tid == 0){
    part[b] = make_float2(fminf(fminf(smn[0],smn[1]),fminf(smn[2],smn[3])),
                          fmaxf(fmaxf(smx[0],smx[1]),fmaxf(smx[2],smx[3])));
  }
}

// reduce 64 per-block partials per image -> stats (one 64-thread block per image)
__global__ void k_edred(const float2* __restrict__ part, uint32_t* __restrict__ stats){
  int img = blockIdx.x;
  int ln = threadIdx.x;
  float2 v = part[img*64 + ln];
  float mn = v.x, mx = v.y;
  for (int off = 32; off >= 1; off >>= 1){
    mn = fminf(mn, __shfl_down(mn, off));
    mx = fmaxf(mx, __shfl_down(mx, off));
  }
  if (ln == 0){
    stats[img*4+0] = __float_as_uint(mn);
    stats[img*4+1] = __float_as_uint(mx);
  }
}

// ---------------- fuse: normalize both maps, sigmoid ----------------
__global__ void k_final(const float* __restrict__ ed, const uint16_t* __restrict__ comb,
                        const uint32_t* __restrict__ hist, const uint32_t* __restrict__ stats,
                        const float* __restrict__ alpha, const float* __restrict__ beta,
                        float* __restrict__ out)
{
#pragma clang fp contract(off)
  int idx = blockIdx.x * 256 + threadIdx.x;
  int img = idx >> 18;
  float a = alpha[0], b = beta[0];
  float mne = __uint_as_float(stats[img*4+0]);
  float mxe = __uint_as_float(stats[img*4+1]);
  float mns = __uint_as_float(stats[img*4+2]);
  float mxs = __uint_as_float(stats[img*4+3]);
  float e  = ed[idx];
  float sp = -logf((float)hist[img*NBINS + comb[idx]] / 262144.0f + 1e-9f);
  float en = (e  - mne) / (mxe - mne + 1e-9f);
  float sn = (sp - mns) / (mxs - mns + 1e-9f);
  float f  = a*en + b*sn;
  out[idx] = 1.0f / (1.0f + expf(-f));
}

extern "C" void kernel_launch(void* const* d_in, const int* in_sizes, int n_in,
                              void* d_out, int out_size, void* d_ws, size_t ws_size,
                              hipStream_t stream)
{
  const float* x     = (const float*)d_in[0];
  const float* mean  = (const float*)d_in[1];
  const float* stdv  = (const float*)d_in[2];
  const float* alpha = (const float*)d_in[3];
  const float* beta  = (const float*)d_in[4];
  float* out = (float*)d_out;

  char* ws = (char*)d_ws;
  float*    gray  = (float*)ws;                                   // 16 MB
  uint16_t* comb  = (uint16_t*)(ws + (16u << 20));                // 8 MB
  float2*   part  = (float2*)(ws + (24u << 20));                  // 8 KB
  uint32_t* hist  = (uint32_t*)(ws + (28u << 20));                // 256 KB
  u64*      Ab    = (u64*)(ws + (28u << 20) + (1u << 18));               // 512 KB
  u64*      Sb    = (u64*)(ws + (28u << 20) + (1u << 18) + (1u << 19));  // 512 KB
  uint32_t* stats = (uint32_t*)(ws + (28u << 20) + (1u << 18) + (2u << 19));  // 256 B

  hipLaunchKernelGGL(k_zero,  dim3(64),    dim3(256), 0, stream, (uint4*)hist);
  hipLaunchKernelGGL(k_prep,  dim3(1024),  dim3(256), 0, stream, x, mean, stdv, gray, comb, hist);
  hipLaunchKernelGGL(k_spb,   dim3(NB),    dim3(256), 0, stream, hist, stats);
  hipLaunchKernelGGL(k_canny, dim3(2048),  dim3(256), 0, stream, gray, Ab, Sb);
  hipLaunchKernelGGL(k_hyst,  dim3(NB),    dim3(1024), 0, stream, Ab, Sb);
  hipLaunchKernelGGL(k_b11,   dim3(1024),  dim3(256), 0, stream, Sb, out, part);
  hipLaunchKernelGGL(k_edred, dim3(NB),    dim3(64),  0, stream, part, stats);
  hipLaunchKernelGGL(k_final, dim3(16384), dim3(256), 0, stream, out, comb, hist, stats, alpha, beta, out);
}